// Round 1
// baseline (250.111 us; speedup 1.0000x reference)
//
#include <hip/hip_runtime.h>
#include <math.h>

#define TPB 256

__device__ __forceinline__ float sl1(float x) {
    float a = fabsf(x);
    return a < 1.f ? 0.5f * a * a : a - 0.5f;
}

// ---------------------------------------------------------------------------
// K1: per-batch-row matching. One block per row b.
//  - IoU of 16 objects vs P priors
//  - per-prior max/argmax over objects  (LDS arrays ovl_s / obj_s)
//  - per-object argmax over priors (wave-shuffle + LDS reduce), then the
//    forced assignment obj_p[prior_for_obj[i]] = i, ovl = 1.0 (sequential,
//    last-wins, matching numpy scatter semantics)
//  - second pass: labels/pos/ignore -> meta[], fused SmoothL1 loc-loss for
//    positive priors, per-row n_pos
// ---------------------------------------------------------------------------
template<int NOBJ>
__global__ __launch_bounds__(TPB)
void k_match(const float* __restrict__ boxes, const int* __restrict__ labels,
             const float* __restrict__ priors, const float* __restrict__ plocs,
             int P, unsigned* __restrict__ meta, int* __restrict__ n_pos,
             float* __restrict__ accum, int* __restrict__ n_total)
{
    const int b = blockIdx.x;
    const int tid = threadIdx.x;

    extern __shared__ char smem[];
    float* ovl_s = (float*)smem;                                   // P floats
    unsigned char* obj_s = (unsigned char*)(smem + (size_t)P * 4); // P bytes
    char* base2 = smem + (size_t)P * 4 + (size_t)((P + 15) & ~15);
    float* sbox  = (float*)base2;                       // [9][NOBJ]
    int*   s_lab = (int*)(base2 + 9 * NOBJ * 4);        // [NOBJ]
    float* redv  = (float*)(base2 + 10 * NOBJ * 4);     // [NOBJ][4]
    int*   redp  = (int*)(base2 + 14 * NOBJ * 4);       // [NOBJ][4]
    int*   pf    = (int*)(base2 + 18 * NOBJ * 4);       // [NOBJ]
    int*   s_cnt = (int*)(base2 + 19 * NOBJ * 4);
    float* s_lsum = (float*)(s_cnt + 1);

    // --- load boxes: xyxy, area, cxcy (all derived exactly like the ref) ---
    if (tid < NOBJ) {
        const float4 bx = ((const float4*)boxes)[(size_t)b * NOBJ + tid];
        float x1 = bx.x, y1 = bx.y, x2 = bx.x + bx.z, y2 = bx.y + bx.w;
        sbox[0 * NOBJ + tid] = x1;
        sbox[1 * NOBJ + tid] = y1;
        sbox[2 * NOBJ + tid] = x2;
        sbox[3 * NOBJ + tid] = y2;
        sbox[4 * NOBJ + tid] = (x2 - x1) * (y2 - y1);
        sbox[5 * NOBJ + tid] = (x1 + x2) * 0.5f;
        sbox[6 * NOBJ + tid] = (y1 + y2) * 0.5f;
        sbox[7 * NOBJ + tid] = x2 - x1;
        sbox[8 * NOBJ + tid] = y2 - y1;
        s_lab[tid] = labels[b * NOBJ + tid];
        if (tid == 0) { *s_cnt = 0; *s_lsum = 0.f; }
    }
    __syncthreads();

    // --- pass 1: IoU, per-prior best object, per-object best prior ---------
    float bestv[NOBJ];
    int bestp[NOBJ];
#pragma unroll
    for (int o = 0; o < NOBJ; o++) { bestv[o] = -1.f; bestp[o] = 0x7fffffff; }

    for (int p = tid; p < P; p += TPB) {
        float4 pr = ((const float4*)priors)[p];
        float hx = pr.z * 0.5f, hy = pr.w * 0.5f;
        float px1 = pr.x - hx, py1 = pr.y - hy;
        float px2 = pr.x + hx, py2 = pr.y + hy;
        float parea = (px2 - px1) * (py2 - py1);
        float bv = -1.f; int bo = 0;
#pragma unroll
        for (int o = 0; o < NOBJ; o++) {
            float ltx = fmaxf(sbox[0 * NOBJ + o], px1);
            float lty = fmaxf(sbox[1 * NOBJ + o], py1);
            float rbx = fminf(sbox[2 * NOBJ + o], px2);
            float rby = fminf(sbox[3 * NOBJ + o], py2);
            float w = rbx - ltx; w = w > 0.f ? w : 0.f;
            float h = rby - lty; h = h > 0.f ? h : 0.f;
            float inter = w * h;
            float iou = inter / (sbox[4 * NOBJ + o] + parea - inter);
            if (iou > bv) { bv = iou; bo = o; }            // first-max (strict >)
            if (iou > bestv[o]) { bestv[o] = iou; bestp[o] = p; }
        }
        ovl_s[p] = bv;
        obj_s[p] = (unsigned char)bo;
    }

    // --- per-object argmax over priors: wave reduce then cross-wave --------
#pragma unroll
    for (int o = 0; o < NOBJ; o++) {
        float v = bestv[o]; int pp = bestp[o];
#pragma unroll
        for (int d = 1; d < 64; d <<= 1) {
            float v2 = __shfl_xor(v, d);
            int   q2 = __shfl_xor(pp, d);
            if (v2 > v || (v2 == v && q2 < pp)) { v = v2; pp = q2; }
        }
        if ((tid & 63) == 0) {
            redv[o * 4 + (tid >> 6)] = v;
            redp[o * 4 + (tid >> 6)] = pp;
        }
    }
    __syncthreads();

    if (tid < NOBJ) {
        float v = -2.f; int pp = 0x7fffffff;
        for (int w = 0; w < 4; w++) {
            float v2 = redv[tid * 4 + w];
            int   q2 = redp[tid * 4 + w];
            if (v2 > v || (v2 == v && q2 < pp)) { v = v2; pp = q2; }
        }
        pf[tid] = pp;
    }
    __syncthreads();

    // forced assignment (sequential: duplicate best-priors -> last wins)
    if (tid == 0) {
        for (int i = 0; i < NOBJ; i++) {
            int pp = pf[i];
            obj_s[pp] = (unsigned char)i;
            ovl_s[pp] = 1.0f;
        }
    }
    __syncthreads();

    // --- pass 2: labels / flags / fused localization loss ------------------
    int cnt = 0;
    float lsum = 0.f;
    for (int p = tid; p < P; p += TPB) {
        float ovl = ovl_s[p];
        int o = obj_s[p];
        int lab = s_lab[o];
        if (ovl < 0.5f) lab = 0;
        bool ign = (ovl > 0.4f) && (ovl < 0.5f);
        bool pos = (lab > 0) && !ign;
        meta[(size_t)b * P + p] = (unsigned)lab | (pos ? 256u : 0u) | (ign ? 512u : 0u);
        if (pos) {
            cnt++;
            float4 pr = ((const float4*)priors)[p];
            float cx = sbox[5 * NOBJ + o], cy = sbox[6 * NOBJ + o];
            float bw = sbox[7 * NOBJ + o], bh = sbox[8 * NOBJ + o];
            float g0 = (cx - pr.x) / (pr.z / 10.0f);
            float g1 = (cy - pr.y) / (pr.w / 10.0f);
            float g2 = logf(fabsf(bw / pr.z)) * 5.0f;
            float g3 = logf(fabsf(bh / pr.w)) * 5.0f;
            float4 pl = ((const float4*)plocs)[(size_t)b * P + p];
            lsum += sl1(pl.x - g0) + sl1(pl.y - g1) + sl1(pl.z - g2) + sl1(pl.w - g3);
        }
    }
#pragma unroll
    for (int d = 1; d < 64; d <<= 1) {
        lsum += __shfl_xor(lsum, d);
        cnt  += __shfl_xor(cnt, d);
    }
    if ((tid & 63) == 0) {
        atomicAdd(s_cnt, cnt);
        atomicAdd(s_lsum, lsum);
    }
    __syncthreads();
    if (tid == 0) {
        n_pos[b] = *s_cnt;
        atomicAdd(n_total, *s_cnt);
        atomicAdd(&accum[0], *s_lsum);
    }
}

// ---------------------------------------------------------------------------
// K2: cross-entropy per prior. 16-lane group per prior (4 priors per wave).
// ce = logsumexp(scores) - scores[label]; writes ce_neg (0 where pos|ignore),
// accumulates positive CE into a 64-slot hashed accumulator.
// ---------------------------------------------------------------------------
__global__ __launch_bounds__(TPB)
void k_ce(const float* __restrict__ scores, const unsigned* __restrict__ meta,
          int BP, int C, float* __restrict__ ce_neg, float* __restrict__ pos_part)
{
    const int tid = threadIdx.x;
    const int g = blockIdx.x * (TPB / 16) + (tid >> 4);
    const int l = tid & 15;
    const bool valid = g < BP;
    const int gg = valid ? g : BP - 1;
    const float* s = scores + (size_t)gg * C;

    __shared__ float s_pos;
    if (tid == 0) s_pos = 0.f;
    __syncthreads();

    float v[6];
    float m = -INFINITY;
#pragma unroll
    for (int j = 0; j < 6; j++) {
        int idx = l + 16 * j;
        v[j] = (idx < C) ? s[idx] : -INFINITY;
        m = fmaxf(m, v[j]);
    }
#pragma unroll
    for (int d = 1; d < 16; d <<= 1) m = fmaxf(m, __shfl_xor(m, d));

    float se = 0.f;
#pragma unroll
    for (int j = 0; j < 6; j++) se += __expf(v[j] - m);
#pragma unroll
    for (int d = 1; d < 16; d <<= 1) se += __shfl_xor(se, d);

    if (l == 0 && valid) {
        unsigned mt = meta[g];
        int lab = (int)(mt & 255u);
        float ce = logf(se) + m - s[lab];
        bool pos = (mt >> 8) & 1u;
        bool ign = (mt >> 9) & 1u;
        ce_neg[g] = (pos || ign) ? 0.f : ce;
        if (pos) atomicAdd(&s_pos, ce);
    }
    __syncthreads();
    if (tid == 0 && s_pos != 0.f)
        atomicAdd(&pos_part[blockIdx.x & 63], s_pos);
}

// ---------------------------------------------------------------------------
// K3: per-row exact radix-select (4x8-bit, msb first) for sum of top-k of
// ce_neg (k = 3*n_pos). Values are >= 0 so uint bit order == float order.
// hard_sum = sum(values > t) + k_rem * t   (t = k-th largest, exact bits)
// ---------------------------------------------------------------------------
__global__ __launch_bounds__(TPB)
void k_topk(const float* __restrict__ ce_neg, const int* __restrict__ n_pos,
            int P, float* __restrict__ accum)
{
    const int b = blockIdx.x;
    const float* row = ce_neg + (size_t)b * P;
    __shared__ unsigned cnt[256];
    __shared__ float sm[256];
    __shared__ float s_sumhigh;
    __shared__ unsigned s_pref;
    __shared__ int s_krem;

    int k = 3 * n_pos[b];
    if (k > P) k = P;
    if (k <= 0) return;

    if (threadIdx.x == 0) { s_sumhigh = 0.f; s_pref = 0u; s_krem = k; }
    __syncthreads();

    for (int shift = 24; shift >= 0; shift -= 8) {
        cnt[threadIdx.x] = 0u;
        sm[threadIdx.x] = 0.f;
        __syncthreads();
        unsigned pref = s_pref;
        int high = shift + 8;
        for (int p = threadIdx.x; p < P; p += TPB) {
            float vv = row[p];
            unsigned u = __float_as_uint(vv);
            if (high >= 32 || ((u >> high) == (pref >> high))) {
                unsigned bin = (u >> shift) & 255u;
                atomicAdd(&cnt[bin], 1u);
                atomicAdd(&sm[bin], vv);
            }
        }
        __syncthreads();
        if (threadIdx.x == 0) {
            int krem = s_krem;
            float sh = s_sumhigh;
            unsigned p2 = s_pref;
            for (int bin = 255; bin >= 0; --bin) {
                if ((int)cnt[bin] < krem) { krem -= (int)cnt[bin]; sh += sm[bin]; }
                else { p2 |= ((unsigned)bin) << shift; break; }
            }
            s_krem = krem; s_sumhigh = sh; s_pref = p2;
        }
        __syncthreads();
    }

    if (threadIdx.x == 0) {
        float t = __uint_as_float(s_pref);
        float hard = s_sumhigh + (float)s_krem * t;
        atomicAdd(&accum[2], hard);
    }
}

// ---------------------------------------------------------------------------
// K4: combine
// ---------------------------------------------------------------------------
__global__ void k_final(const float* __restrict__ accum, const int* __restrict__ n_total,
                        const float* __restrict__ pos_part, float* __restrict__ out)
{
    float ps = 0.f;
    for (int i = 0; i < 64; i++) ps += pos_part[i];
    float n = (float)(*n_total);
    float conf = (accum[2] + ps) / n;
    float loc = accum[0] / (n * 4.0f);
    out[0] = conf + loc;
    out[1] = conf;
    out[2] = loc;
}

extern "C" void kernel_launch(void* const* d_in, const int* in_sizes, int n_in,
                              void* d_out, int out_size, void* d_ws, size_t ws_size,
                              hipStream_t stream)
{
    const float* plocs  = (const float*)d_in[0];   // [B,P,4]
    const float* scores = (const float*)d_in[1];   // [B,P,C]
    const float* boxes  = (const float*)d_in[2];   // [B,NOBJ,4] xywh
    const int*   labels = (const int*)d_in[3];     // [B,NOBJ]
    const float* priors = (const float*)d_in[4];   // [P,4] cxcy

    const int P = in_sizes[4] / 4;
    const int B = in_sizes[0] / (P * 4);
    const int C = in_sizes[1] / (B * P);
    const int BP = B * P;
    // NOBJ fixed at 16 by the benchmark's setup_inputs.

    char* ws = (char*)d_ws;
    float* accum    = (float*)ws;            // [0]=loc_sum, [2]=hard_sum
    int*   n_total  = (int*)(ws + 16);
    int*   n_pos    = (int*)(ws + 64);       // [B]
    float* pos_part = (float*)(ws + 320);    // [64]
    unsigned* meta  = (unsigned*)(ws + 1024);           // [BP]
    float* ce_neg   = (float*)(ws + 1024 + (size_t)BP * 4); // [BP]

    hipMemsetAsync(d_ws, 0, 1024, stream);

    size_t lds = (size_t)P * 4 + (size_t)((P + 15) & ~15) + 1280;
    k_match<16><<<B, TPB, lds, stream>>>(boxes, labels, priors, plocs,
                                         P, meta, n_pos, accum, n_total);

    int ce_blocks = (BP + (TPB / 16) - 1) / (TPB / 16);
    k_ce<<<ce_blocks, TPB, 0, stream>>>(scores, meta, BP, C, ce_neg, pos_part);

    k_topk<<<B, TPB, 0, stream>>>(ce_neg, n_pos, P, accum);

    k_final<<<1, 1, 0, stream>>>(accum, n_total, pos_part, (float*)d_out);
}

// Round 2
// 231.693 us; speedup vs baseline: 1.0795x; 1.0795x over previous
//
#include <hip/hip_runtime.h>
#include <math.h>

#define TPB 256
#define CE_ROWS 64   // rows of scores staged per block in k_ce

__device__ __forceinline__ float sl1(float x) {
    float a = fabsf(x);
    return a < 1.f ? 0.5f * a * a : a - 0.5f;
}

// ---------------------------------------------------------------------------
// K1: per-batch-row matching. One block per row b.
// Outputs: meta[b*P+p] (label | pos<<8 | ign<<9), n_pos[b], loc_sum[b].
// No global atomics, no zero-init needed.
// ---------------------------------------------------------------------------
template<int NOBJ>
__global__ __launch_bounds__(TPB)
void k_match(const float* __restrict__ boxes, const int* __restrict__ labels,
             const float* __restrict__ priors, const float* __restrict__ plocs,
             int P, unsigned* __restrict__ meta, int* __restrict__ n_pos,
             float* __restrict__ loc_sum)
{
    const int b = blockIdx.x;
    const int tid = threadIdx.x;

    extern __shared__ char smem[];
    float* ovl_s = (float*)smem;                                   // P floats
    unsigned char* obj_s = (unsigned char*)(smem + (size_t)P * 4); // P bytes
    char* base2 = smem + (size_t)P * 4 + (size_t)((P + 15) & ~15);
    float* sbox  = (float*)base2;                       // [9][NOBJ]
    int*   s_lab = (int*)(base2 + 9 * NOBJ * 4);        // [NOBJ]
    float* redv  = (float*)(base2 + 10 * NOBJ * 4);     // [NOBJ][4]
    int*   redp  = (int*)(base2 + 14 * NOBJ * 4);       // [NOBJ][4]
    int*   pf    = (int*)(base2 + 18 * NOBJ * 4);       // [NOBJ]
    int*   s_cnt = (int*)(base2 + 19 * NOBJ * 4);
    float* s_lsum = (float*)(s_cnt + 1);

    if (tid < NOBJ) {
        const float4 bx = ((const float4*)boxes)[(size_t)b * NOBJ + tid];
        float x1 = bx.x, y1 = bx.y, x2 = bx.x + bx.z, y2 = bx.y + bx.w;
        sbox[0 * NOBJ + tid] = x1;
        sbox[1 * NOBJ + tid] = y1;
        sbox[2 * NOBJ + tid] = x2;
        sbox[3 * NOBJ + tid] = y2;
        sbox[4 * NOBJ + tid] = (x2 - x1) * (y2 - y1);
        sbox[5 * NOBJ + tid] = (x1 + x2) * 0.5f;
        sbox[6 * NOBJ + tid] = (y1 + y2) * 0.5f;
        sbox[7 * NOBJ + tid] = x2 - x1;
        sbox[8 * NOBJ + tid] = y2 - y1;
        s_lab[tid] = labels[b * NOBJ + tid];
        if (tid == 0) { *s_cnt = 0; *s_lsum = 0.f; }
    }
    __syncthreads();

    // --- pass 1: IoU, per-prior best object, per-object best prior ---------
    float bestv[NOBJ];
    int bestp[NOBJ];
#pragma unroll
    for (int o = 0; o < NOBJ; o++) { bestv[o] = -1.f; bestp[o] = 0x7fffffff; }

    for (int p = tid; p < P; p += TPB) {
        float4 pr = ((const float4*)priors)[p];
        float hx = pr.z * 0.5f, hy = pr.w * 0.5f;
        float px1 = pr.x - hx, py1 = pr.y - hy;
        float px2 = pr.x + hx, py2 = pr.y + hy;
        float parea = (px2 - px1) * (py2 - py1);
        float bv = -1.f; int bo = 0;
#pragma unroll
        for (int o = 0; o < NOBJ; o++) {
            float ltx = fmaxf(sbox[0 * NOBJ + o], px1);
            float lty = fmaxf(sbox[1 * NOBJ + o], py1);
            float rbx = fminf(sbox[2 * NOBJ + o], px2);
            float rby = fminf(sbox[3 * NOBJ + o], py2);
            float w = rbx - ltx; w = w > 0.f ? w : 0.f;
            float h = rby - lty; h = h > 0.f ? h : 0.f;
            float inter = w * h;
            float iou = __fdividef(inter, sbox[4 * NOBJ + o] + parea - inter);
            if (iou > bv) { bv = iou; bo = o; }            // first-max (strict >)
            if (iou > bestv[o]) { bestv[o] = iou; bestp[o] = p; }
        }
        ovl_s[p] = bv;
        obj_s[p] = (unsigned char)bo;
    }

    // --- per-object argmax over priors ------------------------------------
#pragma unroll
    for (int o = 0; o < NOBJ; o++) {
        float v = bestv[o]; int pp = bestp[o];
#pragma unroll
        for (int d = 1; d < 64; d <<= 1) {
            float v2 = __shfl_xor(v, d);
            int   q2 = __shfl_xor(pp, d);
            if (v2 > v || (v2 == v && q2 < pp)) { v = v2; pp = q2; }
        }
        if ((tid & 63) == 0) {
            redv[o * 4 + (tid >> 6)] = v;
            redp[o * 4 + (tid >> 6)] = pp;
        }
    }
    __syncthreads();

    if (tid < NOBJ) {
        float v = -2.f; int pp = 0x7fffffff;
        for (int w = 0; w < 4; w++) {
            float v2 = redv[tid * 4 + w];
            int   q2 = redp[tid * 4 + w];
            if (v2 > v || (v2 == v && q2 < pp)) { v = v2; pp = q2; }
        }
        pf[tid] = pp;
    }
    __syncthreads();

    // forced assignment (sequential: duplicate best-priors -> last wins)
    if (tid == 0) {
        for (int i = 0; i < NOBJ; i++) {
            int pp = pf[i];
            obj_s[pp] = (unsigned char)i;
            ovl_s[pp] = 1.0f;
        }
    }
    __syncthreads();

    // --- pass 2: labels / flags / fused localization loss ------------------
    int cnt = 0;
    float lsum = 0.f;
    for (int p = tid; p < P; p += TPB) {
        float ovl = ovl_s[p];
        int o = obj_s[p];
        int lab = s_lab[o];
        if (ovl < 0.5f) lab = 0;
        bool ign = (ovl > 0.4f) && (ovl < 0.5f);
        bool pos = (lab > 0) && !ign;
        meta[(size_t)b * P + p] = (unsigned)lab | (pos ? 256u : 0u) | (ign ? 512u : 0u);
        if (pos) {
            cnt++;
            float4 pr = ((const float4*)priors)[p];
            float cx = sbox[5 * NOBJ + o], cy = sbox[6 * NOBJ + o];
            float bw = sbox[7 * NOBJ + o], bh = sbox[8 * NOBJ + o];
            float g0 = (cx - pr.x) / (pr.z / 10.0f);
            float g1 = (cy - pr.y) / (pr.w / 10.0f);
            float g2 = logf(fabsf(bw / pr.z)) * 5.0f;
            float g3 = logf(fabsf(bh / pr.w)) * 5.0f;
            float4 pl = ((const float4*)plocs)[(size_t)b * P + p];
            lsum += sl1(pl.x - g0) + sl1(pl.y - g1) + sl1(pl.z - g2) + sl1(pl.w - g3);
        }
    }
#pragma unroll
    for (int d = 1; d < 64; d <<= 1) {
        lsum += __shfl_xor(lsum, d);
        cnt  += __shfl_xor(cnt, d);
    }
    if ((tid & 63) == 0) {
        atomicAdd(s_cnt, cnt);
        atomicAdd(s_lsum, lsum);
    }
    __syncthreads();
    if (tid == 0) {
        n_pos[b] = *s_cnt;
        loc_sum[b] = *s_lsum;
    }
}

// ---------------------------------------------------------------------------
// K2: cross-entropy. Block stages CE_ROWS rows of scores (aligned float4 ->
// LDS), then 16-lane groups compute logsumexp per row from LDS.
// Writes ce_neg[row] (0 where pos|ignore) and pos_blk[blockIdx] (sum of
// positive-prior CE in this block). No atomics to global.
// ---------------------------------------------------------------------------
__global__ __launch_bounds__(TPB)
void k_ce(const float* __restrict__ scores, const unsigned* __restrict__ meta,
          int BP, int C, float* __restrict__ ce_neg, float* __restrict__ pos_blk)
{
    extern __shared__ float sf[];            // CE_ROWS*C floats
    __shared__ float s_pos;

    const int tid = threadIdx.x;
    const int row0 = blockIdx.x * CE_ROWS;
    if (tid == 0) s_pos = 0.f;

    // stage: aligned float4 stream
    {
        const size_t total4 = ((size_t)BP * C) >> 2;     // BP*C divisible by 4
        const size_t base4 = ((size_t)row0 * C) >> 2;    // CE_ROWS*C div by 4
        const int n4 = CE_ROWS * C / 4;
        const float4* src = (const float4*)scores;
        float4* dst = (float4*)sf;
        for (int i = tid; i < n4; i += TPB) {
            if (base4 + i < total4) dst[i] = src[base4 + i];
        }
    }
    __syncthreads();

    const int g = tid >> 4;      // 16 groups
    const int l = tid & 15;

#pragma unroll
    for (int jr = 0; jr < CE_ROWS / 16; jr++) {
        const int r = g + 16 * jr;           // local row
        const int grow = row0 + r;
        if (grow >= BP) continue;
        const float* rowp = sf + (size_t)r * C;

        float m = -INFINITY;
        for (int idx = l; idx < C; idx += 16) m = fmaxf(m, rowp[idx]);
#pragma unroll
        for (int d = 1; d < 16; d <<= 1) m = fmaxf(m, __shfl_xor(m, d));

        float se = 0.f;
        for (int idx = l; idx < C; idx += 16) se += __expf(rowp[idx] - m);
#pragma unroll
        for (int d = 1; d < 16; d <<= 1) se += __shfl_xor(se, d);

        if (l == 0) {
            unsigned mt = meta[grow];
            int lab = (int)(mt & 255u);
            float ce = logf(se) + m - rowp[lab];
            bool pos = (mt >> 8) & 1u;
            bool ign = (mt >> 9) & 1u;
            ce_neg[grow] = (pos || ign) ? 0.f : ce;
            if (pos) atomicAdd(&s_pos, ce);
        }
    }
    __syncthreads();
    if (tid == 0) pos_blk[blockIdx.x] = s_pos;
}

// ---------------------------------------------------------------------------
// K3: per-row exact radix-select (4x8-bit, msb first), sum of top-k of
// ce_neg row (k = 3*n_pos). Per-wave privatized histograms (values >= 0).
// hard[b] = sum(values strictly above thresh bin chain) + k_rem * t
// ---------------------------------------------------------------------------
__global__ __launch_bounds__(TPB)
void k_topk(const float* __restrict__ ce_neg, const int* __restrict__ n_pos,
            int P, float* __restrict__ hard)
{
    const int b = blockIdx.x;
    const float* row = ce_neg + (size_t)b * P;
    __shared__ unsigned cnt[4 * 256];
    __shared__ float sm[4 * 256];
    __shared__ float s_sumhigh;
    __shared__ unsigned s_pref;
    __shared__ int s_krem;

    int k = 3 * n_pos[b];
    if (k > P) k = P;
    if (k <= 0) { if (threadIdx.x == 0) hard[b] = 0.f; return; }

    if (threadIdx.x == 0) { s_sumhigh = 0.f; s_pref = 0u; s_krem = k; }
    const int w = threadIdx.x >> 6;
    __syncthreads();

    for (int shift = 24; shift >= 0; shift -= 8) {
        for (int i = threadIdx.x; i < 1024; i += TPB) { cnt[i] = 0u; sm[i] = 0.f; }
        __syncthreads();
        unsigned pref = s_pref;
        int high = shift + 8;
        for (int p = threadIdx.x; p < P; p += TPB) {
            float vv = row[p];
            unsigned u = __float_as_uint(vv);
            if (high >= 32 || ((u >> high) == (pref >> high))) {
                unsigned bin = (u >> shift) & 255u;
                atomicAdd(&cnt[w * 256 + bin], 1u);
                atomicAdd(&sm[w * 256 + bin], vv);
            }
        }
        __syncthreads();
        // merge the 4 wave-private copies into copy 0 (thread t owns bin t)
        if (threadIdx.x < 256) {
            unsigned c = cnt[threadIdx.x] + cnt[256 + threadIdx.x]
                       + cnt[512 + threadIdx.x] + cnt[768 + threadIdx.x];
            float s = sm[threadIdx.x] + sm[256 + threadIdx.x]
                    + sm[512 + threadIdx.x] + sm[768 + threadIdx.x];
            cnt[threadIdx.x] = c;
            sm[threadIdx.x] = s;
        }
        __syncthreads();
        if (threadIdx.x == 0) {
            int krem = s_krem;
            float sh = s_sumhigh;
            unsigned p2 = s_pref;
            for (int bin = 255; bin >= 0; --bin) {
                if ((int)cnt[bin] < krem) { krem -= (int)cnt[bin]; sh += sm[bin]; }
                else { p2 |= ((unsigned)bin) << shift; break; }
            }
            s_krem = krem; s_sumhigh = sh; s_pref = p2;
        }
        __syncthreads();
    }

    if (threadIdx.x == 0) {
        float t = __uint_as_float(s_pref);
        hard[b] = s_sumhigh + (float)s_krem * t;
    }
}

// ---------------------------------------------------------------------------
// K4: final reduce + combine. One block.
// ---------------------------------------------------------------------------
__global__ __launch_bounds__(TPB)
void k_final(const float* __restrict__ loc_sum, const int* __restrict__ n_pos,
             const float* __restrict__ hard, const float* __restrict__ pos_blk,
             int B, int nblk, float* __restrict__ out)
{
    __shared__ float redf[4];
    __shared__ float redh[4];
    __shared__ float redl[4];
    __shared__ int   redn[4];

    float ps = 0.f;
    for (int i = threadIdx.x; i < nblk; i += TPB) ps += pos_blk[i];
    float lc = 0.f, hd = 0.f; int np = 0;
    for (int i = threadIdx.x; i < B; i += TPB) {
        lc += loc_sum[i]; hd += hard[i]; np += n_pos[i];
    }
#pragma unroll
    for (int d = 1; d < 64; d <<= 1) {
        ps += __shfl_xor(ps, d);
        lc += __shfl_xor(lc, d);
        hd += __shfl_xor(hd, d);
        np += __shfl_xor(np, d);
    }
    if ((threadIdx.x & 63) == 0) {
        int wv = threadIdx.x >> 6;
        redf[wv] = ps; redh[wv] = hd; redl[wv] = lc; redn[wv] = np;
    }
    __syncthreads();
    if (threadIdx.x == 0) {
        float tps = redf[0] + redf[1] + redf[2] + redf[3];
        float thd = redh[0] + redh[1] + redh[2] + redh[3];
        float tlc = redl[0] + redl[1] + redl[2] + redl[3];
        float n = (float)(redn[0] + redn[1] + redn[2] + redn[3]);
        float conf = (thd + tps) / n;
        float loc = tlc / (n * 4.0f);
        out[0] = conf + loc;
        out[1] = conf;
        out[2] = loc;
    }
}

extern "C" void kernel_launch(void* const* d_in, const int* in_sizes, int n_in,
                              void* d_out, int out_size, void* d_ws, size_t ws_size,
                              hipStream_t stream)
{
    const float* plocs  = (const float*)d_in[0];   // [B,P,4]
    const float* scores = (const float*)d_in[1];   // [B,P,C]
    const float* boxes  = (const float*)d_in[2];   // [B,NOBJ,4] xywh
    const int*   labels = (const int*)d_in[3];     // [B,NOBJ]
    const float* priors = (const float*)d_in[4];   // [P,4] cxcy

    const int P = in_sizes[4] / 4;
    const int B = in_sizes[0] / (P * 4);
    const int C = in_sizes[1] / (B * P);
    const int BP = B * P;

    char* ws = (char*)d_ws;
    float* loc_sum = (float*)ws;                        // [B]
    int*   n_pos   = (int*)(ws + 1024);                 // [B]
    float* hard    = (float*)(ws + 2048);               // [B]
    unsigned* meta = (unsigned*)(ws + 4096);            // [BP]
    float* ce_neg  = (float*)(ws + 4096 + (size_t)BP * 4);      // [BP]
    float* pos_blk = (float*)(ws + 4096 + (size_t)BP * 8);      // [nblk]

    size_t ldsA = (size_t)P * 4 + (size_t)((P + 15) & ~15) + 1280;
    k_match<16><<<B, TPB, ldsA, stream>>>(boxes, labels, priors, plocs,
                                          P, meta, n_pos, loc_sum);

    const int nblk = (BP + CE_ROWS - 1) / CE_ROWS;
    size_t ldsB = (size_t)CE_ROWS * C * sizeof(float);
    k_ce<<<nblk, TPB, ldsB, stream>>>(scores, meta, BP, C, ce_neg, pos_blk);

    k_topk<<<B, TPB, 0, stream>>>(ce_neg, n_pos, P, hard);

    k_final<<<1, TPB, 0, stream>>>(loc_sum, n_pos, hard, pos_blk, B, nblk,
                                   (float*)d_out);
}

// Round 3
// 210.362 us; speedup vs baseline: 1.1890x; 1.1014x over previous
//
#include <hip/hip_runtime.h>
#include <math.h>

#define TPB 256
#define MTPB 512      // k_match / k_topk block size
#define CE_ROWS 64    // rows of scores staged per block in k_ce

__device__ __forceinline__ float sl1(float x) {
    float a = fabsf(x);
    return a < 1.f ? 0.5f * a * a : a - 0.5f;
}

// ---------------------------------------------------------------------------
// K1: per-batch-row matching. One block per row b (512 threads, 8 waves).
// Pass-1 box data hoisted to REGISTERS (o is unrolled -> static indexing;
// loads are block-uniform -> scalar loads). Pass 2 indexes boxes by runtime
// o = obj_s[p], so it uses a small LDS table instead.
// Outputs: meta[b*P+p] (label | pos<<8 | ign<<9), n_pos[b], loc_sum[b].
// ---------------------------------------------------------------------------
template<int NOBJ>
__global__ __launch_bounds__(MTPB)
void k_match(const float* __restrict__ boxes, const int* __restrict__ labels,
             const float* __restrict__ priors, const float* __restrict__ plocs,
             int P, unsigned* __restrict__ meta, int* __restrict__ n_pos,
             float* __restrict__ loc_sum)
{
    const int b = blockIdx.x;
    const int tid = threadIdx.x;
    const int NW = MTPB / 64;                 // 8 waves

    extern __shared__ char smem[];
    float* ovl_s = (float*)smem;                                   // P floats
    unsigned char* obj_s = (unsigned char*)(smem + (size_t)P * 4); // P bytes
    char* base2 = smem + (size_t)P * 4 + (size_t)((P + 15) & ~15);
    float* sbox2 = (float*)base2;                       // [4][NOBJ] cx,cy,w,h
    int*   s_lab = (int*)(base2 + 4 * NOBJ * 4);        // [NOBJ]
    float* redv  = (float*)(base2 + 5 * NOBJ * 4);      // [NOBJ][NW]
    int*   redp  = (int*)(base2 + (5 + NW) * NOBJ * 4); // [NOBJ][NW]
    int*   pf    = (int*)(base2 + (5 + 2 * NW) * NOBJ * 4); // [NOBJ]
    int*   s_cnt = pf + NOBJ;
    float* s_lsum = (float*)(s_cnt + 1);

    // ---- hoist all pass-1 box data into registers (uniform scalar loads) --
    float bx1[NOBJ], by1[NOBJ], bx2[NOBJ], by2[NOBJ], bar[NOBJ];
#pragma unroll
    for (int o = 0; o < NOBJ; o++) {
        const float4 bx = ((const float4*)boxes)[(size_t)b * NOBJ + o];
        bx1[o] = bx.x; by1[o] = bx.y;
        bx2[o] = bx.x + bx.z; by2[o] = bx.y + bx.w;
        bar[o] = (bx2[o] - bx1[o]) * (by2[o] - by1[o]);   // exact ref formula
    }
    // small LDS table for pass 2 (runtime-indexed)
    if (tid < NOBJ) {
        sbox2[0 * NOBJ + tid] = (bx1[tid] + bx2[tid]) * 0.5f;  // cx
        sbox2[1 * NOBJ + tid] = (by1[tid] + by2[tid]) * 0.5f;  // cy
        sbox2[2 * NOBJ + tid] = bx2[tid] - bx1[tid];           // w
        sbox2[3 * NOBJ + tid] = by2[tid] - by1[tid];           // h
        s_lab[tid] = labels[b * NOBJ + tid];
        if (tid == 0) { *s_cnt = 0; *s_lsum = 0.f; }
    }

    // --- pass 1: IoU, per-prior best object, per-object best prior ---------
    float bestv[NOBJ];
    int bestp[NOBJ];
#pragma unroll
    for (int o = 0; o < NOBJ; o++) { bestv[o] = -1.f; bestp[o] = 0x7fffffff; }

    for (int p = tid; p < P; p += MTPB) {
        float4 pr = ((const float4*)priors)[p];
        float hx = pr.z * 0.5f, hy = pr.w * 0.5f;
        float px1 = pr.x - hx, py1 = pr.y - hy;
        float px2 = pr.x + hx, py2 = pr.y + hy;
        float parea = (px2 - px1) * (py2 - py1);
        float bv = -1.f; int bo = 0;
#pragma unroll
        for (int o = 0; o < NOBJ; o++) {
            float ltx = fmaxf(bx1[o], px1);
            float lty = fmaxf(by1[o], py1);
            float rbx = fminf(bx2[o], px2);
            float rby = fminf(by2[o], py2);
            float w = rbx - ltx; w = w > 0.f ? w : 0.f;
            float h = rby - lty; h = h > 0.f ? h : 0.f;
            float inter = w * h;
            float iou = __fdividef(inter, bar[o] + parea - inter);
            if (iou > bv) { bv = iou; bo = o; }            // first-max (strict >)
            if (iou > bestv[o]) { bestv[o] = iou; bestp[o] = p; }
        }
        ovl_s[p] = bv;
        obj_s[p] = (unsigned char)bo;
    }

    // --- per-object argmax over priors ------------------------------------
#pragma unroll
    for (int o = 0; o < NOBJ; o++) {
        float v = bestv[o]; int pp = bestp[o];
#pragma unroll
        for (int d = 1; d < 64; d <<= 1) {
            float v2 = __shfl_xor(v, d);
            int   q2 = __shfl_xor(pp, d);
            if (v2 > v || (v2 == v && q2 < pp)) { v = v2; pp = q2; }
        }
        if ((tid & 63) == 0) {
            redv[o * NW + (tid >> 6)] = v;
            redp[o * NW + (tid >> 6)] = pp;
        }
    }
    __syncthreads();

    if (tid < NOBJ) {
        float v = -2.f; int pp = 0x7fffffff;
        for (int w = 0; w < NW; w++) {
            float v2 = redv[tid * NW + w];
            int   q2 = redp[tid * NW + w];
            if (v2 > v || (v2 == v && q2 < pp)) { v = v2; pp = q2; }
        }
        pf[tid] = pp;
    }
    __syncthreads();

    // forced assignment (sequential: duplicate best-priors -> last wins)
    if (tid == 0) {
        for (int i = 0; i < NOBJ; i++) {
            int pp = pf[i];
            obj_s[pp] = (unsigned char)i;
            ovl_s[pp] = 1.0f;
        }
    }
    __syncthreads();

    // --- pass 2: labels / flags / fused localization loss ------------------
    int cnt = 0;
    float lsum = 0.f;
    for (int p = tid; p < P; p += MTPB) {
        float ovl = ovl_s[p];
        int o = obj_s[p];
        int lab = s_lab[o];
        if (ovl < 0.5f) lab = 0;
        bool ign = (ovl > 0.4f) && (ovl < 0.5f);
        bool pos = (lab > 0) && !ign;
        meta[(size_t)b * P + p] = (unsigned)lab | (pos ? 256u : 0u) | (ign ? 512u : 0u);
        if (pos) {
            cnt++;
            float4 pr = ((const float4*)priors)[p];
            float cx = sbox2[0 * NOBJ + o], cy = sbox2[1 * NOBJ + o];
            float bw = sbox2[2 * NOBJ + o], bh = sbox2[3 * NOBJ + o];
            float g0 = (cx - pr.x) / (pr.z / 10.0f);
            float g1 = (cy - pr.y) / (pr.w / 10.0f);
            float g2 = logf(fabsf(bw / pr.z)) * 5.0f;
            float g3 = logf(fabsf(bh / pr.w)) * 5.0f;
            float4 pl = ((const float4*)plocs)[(size_t)b * P + p];
            lsum += sl1(pl.x - g0) + sl1(pl.y - g1) + sl1(pl.z - g2) + sl1(pl.w - g3);
        }
    }
#pragma unroll
    for (int d = 1; d < 64; d <<= 1) {
        lsum += __shfl_xor(lsum, d);
        cnt  += __shfl_xor(cnt, d);
    }
    if ((tid & 63) == 0) {
        atomicAdd(s_cnt, cnt);
        atomicAdd(s_lsum, lsum);
    }
    __syncthreads();
    if (tid == 0) {
        n_pos[b] = *s_cnt;
        loc_sum[b] = *s_lsum;
    }
}

// ---------------------------------------------------------------------------
// K2: cross-entropy. Block stages CE_ROWS rows of scores (aligned float4 ->
// LDS), then 16-lane groups compute logsumexp per row from LDS.
// ---------------------------------------------------------------------------
__global__ __launch_bounds__(TPB)
void k_ce(const float* __restrict__ scores, const unsigned* __restrict__ meta,
          int BP, int C, float* __restrict__ ce_neg, float* __restrict__ pos_blk)
{
    extern __shared__ float sf[];            // CE_ROWS*C floats
    __shared__ float s_pos;

    const int tid = threadIdx.x;
    const int row0 = blockIdx.x * CE_ROWS;
    if (tid == 0) s_pos = 0.f;

    // stage: aligned float4 stream
    {
        const size_t total4 = ((size_t)BP * C) >> 2;
        const size_t base4 = ((size_t)row0 * C) >> 2;
        const int n4 = CE_ROWS * C / 4;
        const float4* src = (const float4*)scores;
        float4* dst = (float4*)sf;
        for (int i = tid; i < n4; i += TPB) {
            if (base4 + i < total4) dst[i] = src[base4 + i];
        }
    }
    __syncthreads();

    const int g = tid >> 4;      // 16 groups
    const int l = tid & 15;

#pragma unroll
    for (int jr = 0; jr < CE_ROWS / 16; jr++) {
        const int r = g + 16 * jr;           // local row
        const int grow = row0 + r;
        if (grow >= BP) continue;
        const float* rowp = sf + (size_t)r * C;

        float m = -INFINITY;
        for (int idx = l; idx < C; idx += 16) m = fmaxf(m, rowp[idx]);
#pragma unroll
        for (int d = 1; d < 16; d <<= 1) m = fmaxf(m, __shfl_xor(m, d));

        float se = 0.f;
        for (int idx = l; idx < C; idx += 16) se += __expf(rowp[idx] - m);
#pragma unroll
        for (int d = 1; d < 16; d <<= 1) se += __shfl_xor(se, d);

        if (l == 0) {
            unsigned mt = meta[grow];
            int lab = (int)(mt & 255u);
            float ce = __logf(se) + m - rowp[lab];
            bool pos = (mt >> 8) & 1u;
            bool ign = (mt >> 9) & 1u;
            ce_neg[grow] = (pos || ign) ? 0.f : ce;
            if (pos) atomicAdd(&s_pos, ce);
        }
    }
    __syncthreads();
    if (tid == 0) pos_blk[blockIdx.x] = s_pos;
}

// ---------------------------------------------------------------------------
// K3: per-row exact radix-select (4x8-bit, msb first), sum of top-k of
// ce_neg row (k = 3*n_pos). 512 threads, 8 wave-private histogram copies.
// ---------------------------------------------------------------------------
__global__ __launch_bounds__(MTPB)
void k_topk(const float* __restrict__ ce_neg, const int* __restrict__ n_pos,
            int P, float* __restrict__ hard)
{
    const int b = blockIdx.x;
    const float* row = ce_neg + (size_t)b * P;
    __shared__ unsigned cnt[8 * 256];
    __shared__ float sm[8 * 256];
    __shared__ float s_sumhigh;
    __shared__ unsigned s_pref;
    __shared__ int s_krem;

    int k = 3 * n_pos[b];
    if (k > P) k = P;
    if (k <= 0) { if (threadIdx.x == 0) hard[b] = 0.f; return; }

    if (threadIdx.x == 0) { s_sumhigh = 0.f; s_pref = 0u; s_krem = k; }
    const int w = threadIdx.x >> 6;
    __syncthreads();

    for (int shift = 24; shift >= 0; shift -= 8) {
        for (int i = threadIdx.x; i < 2048; i += MTPB) { cnt[i] = 0u; sm[i] = 0.f; }
        __syncthreads();
        unsigned pref = s_pref;
        int high = shift + 8;
        for (int p = threadIdx.x; p < P; p += MTPB) {
            float vv = row[p];
            unsigned u = __float_as_uint(vv);
            if (high >= 32 || ((u >> high) == (pref >> high))) {
                unsigned bin = (u >> shift) & 255u;
                atomicAdd(&cnt[w * 256 + bin], 1u);
                atomicAdd(&sm[w * 256 + bin], vv);
            }
        }
        __syncthreads();
        if (threadIdx.x < 256) {
            unsigned c = 0u; float s = 0.f;
#pragma unroll
            for (int cc = 0; cc < 8; cc++) {
                c += cnt[cc * 256 + threadIdx.x];
                s += sm[cc * 256 + threadIdx.x];
            }
            cnt[threadIdx.x] = c;
            sm[threadIdx.x] = s;
        }
        __syncthreads();
        if (threadIdx.x == 0) {
            int krem = s_krem;
            float sh = s_sumhigh;
            unsigned p2 = s_pref;
            for (int bin = 255; bin >= 0; --bin) {
                if ((int)cnt[bin] < krem) { krem -= (int)cnt[bin]; sh += sm[bin]; }
                else { p2 |= ((unsigned)bin) << shift; break; }
            }
            s_krem = krem; s_sumhigh = sh; s_pref = p2;
        }
        __syncthreads();
    }

    if (threadIdx.x == 0) {
        float t = __uint_as_float(s_pref);
        hard[b] = s_sumhigh + (float)s_krem * t;
    }
}

// ---------------------------------------------------------------------------
// K4: final reduce + combine. One block.
// ---------------------------------------------------------------------------
__global__ __launch_bounds__(TPB)
void k_final(const float* __restrict__ loc_sum, const int* __restrict__ n_pos,
             const float* __restrict__ hard, const float* __restrict__ pos_blk,
             int B, int nblk, float* __restrict__ out)
{
    __shared__ float redf[4];
    __shared__ float redh[4];
    __shared__ float redl[4];
    __shared__ int   redn[4];

    float ps = 0.f;
    for (int i = threadIdx.x; i < nblk; i += TPB) ps += pos_blk[i];
    float lc = 0.f, hd = 0.f; int np = 0;
    for (int i = threadIdx.x; i < B; i += TPB) {
        lc += loc_sum[i]; hd += hard[i]; np += n_pos[i];
    }
#pragma unroll
    for (int d = 1; d < 64; d <<= 1) {
        ps += __shfl_xor(ps, d);
        lc += __shfl_xor(lc, d);
        hd += __shfl_xor(hd, d);
        np += __shfl_xor(np, d);
    }
    if ((threadIdx.x & 63) == 0) {
        int wv = threadIdx.x >> 6;
        redf[wv] = ps; redh[wv] = hd; redl[wv] = lc; redn[wv] = np;
    }
    __syncthreads();
    if (threadIdx.x == 0) {
        float tps = redf[0] + redf[1] + redf[2] + redf[3];
        float thd = redh[0] + redh[1] + redh[2] + redh[3];
        float tlc = redl[0] + redl[1] + redl[2] + redl[3];
        float n = (float)(redn[0] + redn[1] + redn[2] + redn[3]);
        float conf = (thd + tps) / n;
        float loc = tlc / (n * 4.0f);
        out[0] = conf + loc;
        out[1] = conf;
        out[2] = loc;
    }
}

extern "C" void kernel_launch(void* const* d_in, const int* in_sizes, int n_in,
                              void* d_out, int out_size, void* d_ws, size_t ws_size,
                              hipStream_t stream)
{
    const float* plocs  = (const float*)d_in[0];   // [B,P,4]
    const float* scores = (const float*)d_in[1];   // [B,P,C]
    const float* boxes  = (const float*)d_in[2];   // [B,NOBJ,4] xywh
    const int*   labels = (const int*)d_in[3];     // [B,NOBJ]
    const float* priors = (const float*)d_in[4];   // [P,4] cxcy

    const int P = in_sizes[4] / 4;
    const int B = in_sizes[0] / (P * 4);
    const int C = in_sizes[1] / (B * P);
    const int BP = B * P;

    char* ws = (char*)d_ws;
    float* loc_sum = (float*)ws;                        // [B]
    int*   n_pos   = (int*)(ws + 1024);                 // [B]
    float* hard    = (float*)(ws + 2048);               // [B]
    unsigned* meta = (unsigned*)(ws + 4096);            // [BP]
    float* ce_neg  = (float*)(ws + 4096 + (size_t)BP * 4);      // [BP]
    float* pos_blk = (float*)(ws + 4096 + (size_t)BP * 8);      // [nblk]

    size_t ldsA = (size_t)P * 4 + (size_t)((P + 15) & ~15) + 2048;
    k_match<16><<<B, MTPB, ldsA, stream>>>(boxes, labels, priors, plocs,
                                           P, meta, n_pos, loc_sum);

    const int nblk = (BP + CE_ROWS - 1) / CE_ROWS;
    size_t ldsB = (size_t)CE_ROWS * C * sizeof(float);
    k_ce<<<nblk, TPB, ldsB, stream>>>(scores, meta, BP, C, ce_neg, pos_blk);

    k_topk<<<B, MTPB, 0, stream>>>(ce_neg, n_pos, P, hard);

    k_final<<<1, TPB, 0, stream>>>(loc_sum, n_pos, hard, pos_blk, B, nblk,
                                   (float*)d_out);
}

// Round 4
// 172.087 us; speedup vs baseline: 1.4534x; 1.2224x over previous
//
#include <hip/hip_runtime.h>
#include <math.h>

#define TPB 256
#define MTPB 512       // k_match / k_topk block size
#define CE_BLOCKS 2048 // k_ce grid (8 blocks/CU on 256 CUs)

__device__ __forceinline__ float sl1(float x) {
    float a = fabsf(x);
    return a < 1.f ? 0.5f * a * a : a - 0.5f;
}

// ---------------------------------------------------------------------------
// K1: per-batch-row matching. One block per row b (512 threads, 8 waves).
// Pass-1 box data in registers (unrolled o -> static indexing, uniform loads).
// Outputs: meta[b*P+p] (label | pos<<8 | ign<<9), n_pos[b], loc_sum[b].
// Also zeroes the ticket used by K3's last-block fused final.
// ---------------------------------------------------------------------------
template<int NOBJ>
__global__ __launch_bounds__(MTPB)
void k_match(const float* __restrict__ boxes, const int* __restrict__ labels,
             const float* __restrict__ priors, const float* __restrict__ plocs,
             int P, unsigned* __restrict__ meta, int* __restrict__ n_pos,
             float* __restrict__ loc_sum, unsigned* __restrict__ ticket)
{
    const int b = blockIdx.x;
    const int tid = threadIdx.x;
    const int NW = MTPB / 64;                 // 8 waves

    if (b == 0 && tid == 0) *ticket = 0u;     // consumed by K3 (next-next kernel)

    extern __shared__ char smem[];
    float* ovl_s = (float*)smem;                                   // P floats
    unsigned char* obj_s = (unsigned char*)(smem + (size_t)P * 4); // P bytes
    char* base2 = smem + (size_t)P * 4 + (size_t)((P + 15) & ~15);
    float* sbox2 = (float*)base2;                       // [4][NOBJ] cx,cy,w,h
    int*   s_lab = (int*)(base2 + 4 * NOBJ * 4);        // [NOBJ]
    float* redv  = (float*)(base2 + 5 * NOBJ * 4);      // [NOBJ][NW]
    int*   redp  = (int*)(base2 + (5 + NW) * NOBJ * 4); // [NOBJ][NW]
    int*   pf    = (int*)(base2 + (5 + 2 * NW) * NOBJ * 4); // [NOBJ]
    int*   s_cnt = pf + NOBJ;
    float* s_lsum = (float*)(s_cnt + 1);

    // ---- hoist all pass-1 box data into registers (uniform loads) ---------
    float bx1[NOBJ], by1[NOBJ], bx2[NOBJ], by2[NOBJ], bar[NOBJ];
#pragma unroll
    for (int o = 0; o < NOBJ; o++) {
        const float4 bx = ((const float4*)boxes)[(size_t)b * NOBJ + o];
        bx1[o] = bx.x; by1[o] = bx.y;
        bx2[o] = bx.x + bx.z; by2[o] = bx.y + bx.w;
        bar[o] = (bx2[o] - bx1[o]) * (by2[o] - by1[o]);
    }
    // small LDS table for pass 2 (runtime-indexed by o)
    if (tid < NOBJ) {
        sbox2[0 * NOBJ + tid] = (bx1[tid] + bx2[tid]) * 0.5f;  // cx
        sbox2[1 * NOBJ + tid] = (by1[tid] + by2[tid]) * 0.5f;  // cy
        sbox2[2 * NOBJ + tid] = bx2[tid] - bx1[tid];           // w
        sbox2[3 * NOBJ + tid] = by2[tid] - by1[tid];           // h
        s_lab[tid] = labels[b * NOBJ + tid];
        if (tid == 0) { *s_cnt = 0; *s_lsum = 0.f; }
    }

    // --- pass 1: IoU, per-prior best object, per-object best prior ---------
    float bestv[NOBJ];
    int bestp[NOBJ];
#pragma unroll
    for (int o = 0; o < NOBJ; o++) { bestv[o] = -1.f; bestp[o] = 0x7fffffff; }

    for (int p = tid; p < P; p += MTPB) {
        float4 pr = ((const float4*)priors)[p];
        float hx = pr.z * 0.5f, hy = pr.w * 0.5f;
        float px1 = pr.x - hx, py1 = pr.y - hy;
        float px2 = pr.x + hx, py2 = pr.y + hy;
        float parea = (px2 - px1) * (py2 - py1);
        float bv = -1.f; int bo = 0;
#pragma unroll
        for (int o = 0; o < NOBJ; o++) {
            float ltx = fmaxf(bx1[o], px1);
            float lty = fmaxf(by1[o], py1);
            float rbx = fminf(bx2[o], px2);
            float rby = fminf(by2[o], py2);
            float w = rbx - ltx; w = w > 0.f ? w : 0.f;
            float h = rby - lty; h = h > 0.f ? h : 0.f;
            float inter = w * h;
            float iou = __fdividef(inter, bar[o] + parea - inter);
            if (iou > bv) { bv = iou; bo = o; }            // first-max (strict >)
            if (iou > bestv[o]) { bestv[o] = iou; bestp[o] = p; }
        }
        ovl_s[p] = bv;
        obj_s[p] = (unsigned char)bo;
    }

    // --- per-object argmax over priors ------------------------------------
#pragma unroll
    for (int o = 0; o < NOBJ; o++) {
        float v = bestv[o]; int pp = bestp[o];
#pragma unroll
        for (int d = 1; d < 64; d <<= 1) {
            float v2 = __shfl_xor(v, d);
            int   q2 = __shfl_xor(pp, d);
            if (v2 > v || (v2 == v && q2 < pp)) { v = v2; pp = q2; }
        }
        if ((tid & 63) == 0) {
            redv[o * NW + (tid >> 6)] = v;
            redp[o * NW + (tid >> 6)] = pp;
        }
    }
    __syncthreads();

    if (tid < NOBJ) {
        float v = -2.f; int pp = 0x7fffffff;
        for (int w = 0; w < NW; w++) {
            float v2 = redv[tid * NW + w];
            int   q2 = redp[tid * NW + w];
            if (v2 > v || (v2 == v && q2 < pp)) { v = v2; pp = q2; }
        }
        pf[tid] = pp;
    }
    __syncthreads();

    // forced assignment (sequential: duplicate best-priors -> last wins)
    if (tid == 0) {
        for (int i = 0; i < NOBJ; i++) {
            int pp = pf[i];
            obj_s[pp] = (unsigned char)i;
            ovl_s[pp] = 1.0f;
        }
    }
    __syncthreads();

    // --- pass 2: labels / flags / fused localization loss ------------------
    int cnt = 0;
    float lsum = 0.f;
    for (int p = tid; p < P; p += MTPB) {
        float ovl = ovl_s[p];
        int o = obj_s[p];
        int lab = s_lab[o];
        if (ovl < 0.5f) lab = 0;
        bool ign = (ovl > 0.4f) && (ovl < 0.5f);
        bool pos = (lab > 0) && !ign;
        meta[(size_t)b * P + p] = (unsigned)lab | (pos ? 256u : 0u) | (ign ? 512u : 0u);
        if (pos) {
            cnt++;
            float4 pr = ((const float4*)priors)[p];
            float cx = sbox2[0 * NOBJ + o], cy = sbox2[1 * NOBJ + o];
            float bw = sbox2[2 * NOBJ + o], bh = sbox2[3 * NOBJ + o];
            float g0 = (cx - pr.x) / (pr.z / 10.0f);
            float g1 = (cy - pr.y) / (pr.w / 10.0f);
            float g2 = logf(fabsf(bw / pr.z)) * 5.0f;
            float g3 = logf(fabsf(bh / pr.w)) * 5.0f;
            float4 pl = ((const float4*)plocs)[(size_t)b * P + p];
            lsum += sl1(pl.x - g0) + sl1(pl.y - g1) + sl1(pl.z - g2) + sl1(pl.w - g3);
        }
    }
#pragma unroll
    for (int d = 1; d < 64; d <<= 1) {
        lsum += __shfl_xor(lsum, d);
        cnt  += __shfl_xor(cnt, d);
    }
    if ((tid & 63) == 0) {
        atomicAdd(s_cnt, cnt);
        atomicAdd(s_lsum, lsum);
    }
    __syncthreads();
    if (tid == 0) {
        n_pos[b] = *s_cnt;
        loc_sum[b] = *s_lsum;
    }
}

// ---------------------------------------------------------------------------
// K2: cross-entropy, direct global->register (no LDS staging, no barrier).
// 16-lane group per row; grid-stride over 16-row tiles. The label score is
// picked from the group's own registers (cndmask chain + one shuffle) --
// no dependent s[lab] gather. Requires C <= 96 (bench: C=91).
// ---------------------------------------------------------------------------
__global__ __launch_bounds__(TPB)
void k_ce(const float* __restrict__ scores, const unsigned* __restrict__ meta,
          int BP, int C, float* __restrict__ ce_neg, float* __restrict__ pos_blk)
{
    const int tid = threadIdx.x;
    const int g = tid >> 4;              // group within block (16 groups)
    const int wg = (tid >> 4) & 3;       // group within wave (4 groups)
    const int l = tid & 15;
    const int tiles = BP >> 4;           // BP divisible by 16 (B*P = 64*8732)

    float psum = 0.f;

    for (int t = blockIdx.x; t < tiles; t += gridDim.x) {
        const int row = (t << 4) + g;
        const unsigned mt = meta[row];   // issued early; broadcast in-group
        const float* s = scores + (size_t)row * C;

        float v[6];
        float m = -INFINITY;
#pragma unroll
        for (int j = 0; j < 6; j++) {
            int idx = l + (j << 4);
            v[j] = (idx < C) ? s[idx] : -INFINITY;
            m = fmaxf(m, v[j]);
        }
#pragma unroll
        for (int d = 1; d < 16; d <<= 1) m = fmaxf(m, __shfl_xor(m, d));

        float se = 0.f;
#pragma unroll
        for (int j = 0; j < 6; j++) se += __expf(v[j] - m);
#pragma unroll
        for (int d = 1; d < 16; d <<= 1) se += __shfl_xor(se, d);

        const int lab = (int)(mt & 255u);
        // static-index select of v[lab>>4] (rule #20: no dynamic reg indexing)
        float pick = v[0];
#pragma unroll
        for (int j = 1; j < 6; j++) pick = ((lab >> 4) == j) ? v[j] : pick;
        float sv = __shfl(pick, (wg << 4) | (lab & 15));   // wave-relative lane

        if (l == 0) {
            float ce = __logf(se) + m - sv;
            bool pos = (mt >> 8) & 1u;
            bool ign = (mt >> 9) & 1u;
            ce_neg[row] = (pos || ign) ? 0.f : ce;
            if (pos) psum += ce;
        }
    }

    // block-reduce psum (only lane0s hold nonzero; others are 0)
#pragma unroll
    for (int d = 1; d < 64; d <<= 1) psum += __shfl_xor(psum, d);
    __shared__ float sp[4];
    if ((tid & 63) == 0) sp[tid >> 6] = psum;
    __syncthreads();
    if (tid == 0) pos_blk[blockIdx.x] = sp[0] + sp[1] + sp[2] + sp[3];
}

// ---------------------------------------------------------------------------
// K3: per-row exact radix-select (4x8-bit, msb first) for sum of top-k of
// ce_neg (k = 3*n_pos), with the final combine fused into the last-arriving
// block (device-scope ticket; hard[] passed via atomicExch/atomic-read).
// Histogram copies padded to stride 257 so the 8 wave-private copies land in
// 8 distinct LDS banks (stride 256 aliased them all to one bank).
// ---------------------------------------------------------------------------
__global__ __launch_bounds__(MTPB)
void k_topk_final(const float* __restrict__ ce_neg, const int* __restrict__ n_pos,
                  const float* __restrict__ loc_sum, const float* __restrict__ pos_blk,
                  int nposblk, int P, int B,
                  float* __restrict__ hard, unsigned* __restrict__ ticket,
                  float* __restrict__ out)
{
    const int b = blockIdx.x;
    const int tid = threadIdx.x;
    const float* row = ce_neg + (size_t)b * P;
    __shared__ unsigned cnt[8 * 257];
    __shared__ float sm[8 * 257];
    __shared__ float s_sumhigh;
    __shared__ unsigned s_pref;
    __shared__ int s_krem;
    __shared__ bool s_last;

    int k = 3 * n_pos[b];
    if (k > P) k = P;

    float hard_b = 0.f;
    if (k > 0) {
        if (tid == 0) { s_sumhigh = 0.f; s_pref = 0u; s_krem = k; }
        const int w = tid >> 6;
        __syncthreads();

        for (int shift = 24; shift >= 0; shift -= 8) {
            for (int i = tid; i < 8 * 257; i += MTPB) { cnt[i] = 0u; sm[i] = 0.f; }
            __syncthreads();
            unsigned pref = s_pref;
            int high = shift + 8;
            for (int p = tid; p < P; p += MTPB) {
                float vv = row[p];
                unsigned u = __float_as_uint(vv);
                if (high >= 32 || ((u >> high) == (pref >> high))) {
                    unsigned bin = (u >> shift) & 255u;
                    atomicAdd(&cnt[w * 257 + bin], 1u);
                    atomicAdd(&sm[w * 257 + bin], vv);
                }
            }
            __syncthreads();
            if (tid < 256) {
                unsigned c = 0u; float s = 0.f;
#pragma unroll
                for (int cc = 0; cc < 8; cc++) {
                    c += cnt[cc * 257 + tid];
                    s += sm[cc * 257 + tid];
                }
                cnt[tid] = c;
                sm[tid] = s;
            }
            __syncthreads();
            if (tid == 0) {
                int krem = s_krem;
                float sh = s_sumhigh;
                unsigned p2 = s_pref;
                for (int bin = 255; bin >= 0; --bin) {
                    if ((int)cnt[bin] < krem) { krem -= (int)cnt[bin]; sh += sm[bin]; }
                    else { p2 |= ((unsigned)bin) << shift; break; }
                }
                s_krem = krem; s_sumhigh = sh; s_pref = p2;
            }
            __syncthreads();
        }
        if (tid == 0) {
            float t = __uint_as_float(s_pref);
            hard_b = s_sumhigh + (float)s_krem * t;
        }
    }

    // ---- publish + ticket (device-scope) ----------------------------------
    if (tid == 0) {
        atomicExch(&hard[b], hard_b);      // coherent publish
        __threadfence();                    // order publish before ticket
        unsigned old = atomicAdd(ticket, 1u);
        s_last = (old == (unsigned)(gridDim.x - 1));
    }
    __syncthreads();
    if (!s_last) return;

    // ---- fused final combine (last block only) -----------------------------
    __threadfence();
    float hd = (tid < B) ? atomicAdd(&hard[tid], 0.f) : 0.f;  // coherent read
    float lc = (tid < B) ? loc_sum[tid] : 0.f;                // prior-kernel data
    int   np = (tid < B) ? n_pos[tid] : 0;
    float ps = 0.f;
    for (int i = tid; i < nposblk; i += MTPB) ps += pos_blk[i];

#pragma unroll
    for (int d = 1; d < 64; d <<= 1) {
        hd += __shfl_xor(hd, d);
        lc += __shfl_xor(lc, d);
        ps += __shfl_xor(ps, d);
        np += __shfl_xor(np, d);
    }
    if ((tid & 63) == 0) {
        int wv = tid >> 6;
        sm[wv] = hd; sm[8 + wv] = lc; sm[16 + wv] = ps;
        cnt[wv] = (unsigned)np;
    }
    __syncthreads();
    if (tid == 0) {
        float thd = 0.f, tlc = 0.f, tps = 0.f; unsigned tnp = 0u;
        for (int wv = 0; wv < MTPB / 64; wv++) {
            thd += sm[wv]; tlc += sm[8 + wv]; tps += sm[16 + wv]; tnp += cnt[wv];
        }
        float n = (float)tnp;
        float conf = (thd + tps) / n;
        float loc = tlc / (n * 4.0f);
        out[0] = conf + loc;
        out[1] = conf;
        out[2] = loc;
    }
}

extern "C" void kernel_launch(void* const* d_in, const int* in_sizes, int n_in,
                              void* d_out, int out_size, void* d_ws, size_t ws_size,
                              hipStream_t stream)
{
    const float* plocs  = (const float*)d_in[0];   // [B,P,4]
    const float* scores = (const float*)d_in[1];   // [B,P,C]
    const float* boxes  = (const float*)d_in[2];   // [B,NOBJ,4] xywh
    const int*   labels = (const int*)d_in[3];     // [B,NOBJ]
    const float* priors = (const float*)d_in[4];   // [P,4] cxcy

    const int P = in_sizes[4] / 4;
    const int B = in_sizes[0] / (P * 4);
    const int C = in_sizes[1] / (B * P);
    const int BP = B * P;

    char* ws = (char*)d_ws;
    float*    loc_sum = (float*)ws;                          // [B]
    int*      n_pos   = (int*)(ws + 1024);                   // [B]
    float*    hard    = (float*)(ws + 2048);                 // [B]
    unsigned* ticket  = (unsigned*)(ws + 3072);              // 1
    unsigned* meta    = (unsigned*)(ws + 4096);              // [BP]
    float*    ce_neg  = (float*)(ws + 4096 + (size_t)BP * 4);// [BP]
    float*    pos_blk = (float*)(ws + 4096 + (size_t)BP * 8);// [CE_BLOCKS]

    size_t ldsA = (size_t)P * 4 + (size_t)((P + 15) & ~15) + 2048;
    k_match<16><<<B, MTPB, ldsA, stream>>>(boxes, labels, priors, plocs,
                                           P, meta, n_pos, loc_sum, ticket);

    k_ce<<<CE_BLOCKS, TPB, 0, stream>>>(scores, meta, BP, C, ce_neg, pos_blk);

    k_topk_final<<<B, MTPB, 0, stream>>>(ce_neg, n_pos, loc_sum, pos_blk,
                                         CE_BLOCKS, P, B, hard, ticket,
                                         (float*)d_out);
}

// Round 5
// 162.663 us; speedup vs baseline: 1.5376x; 1.0579x over previous
//
#include <hip/hip_runtime.h>
#include <math.h>

#define TPB 256
#define MTPB 512       // k_match / k_topk block size
#define CE_BLOCKS 2048 // k_ce grid (8 blocks/CU on 256 CUs)

__device__ __forceinline__ float sl1(float x) {
    float a = fabsf(x);
    return a < 1.f ? 0.5f * a * a : a - 0.5f;
}

// ---------------------------------------------------------------------------
// K1: per-batch-row matching. One block per row b (512 threads, 8 waves).
// Pass-1 box data in registers (unrolled o -> static indexing, uniform loads).
// Outputs: meta[b*P+p] (label | pos<<8 | ign<<9), n_pos[b], loc_sum[b].
// Also zeroes the ticket used by K3's last-block fused final.
// ---------------------------------------------------------------------------
template<int NOBJ>
__global__ __launch_bounds__(MTPB)
void k_match(const float* __restrict__ boxes, const int* __restrict__ labels,
             const float* __restrict__ priors, const float* __restrict__ plocs,
             int P, unsigned* __restrict__ meta, int* __restrict__ n_pos,
             float* __restrict__ loc_sum, unsigned* __restrict__ ticket)
{
    const int b = blockIdx.x;
    const int tid = threadIdx.x;
    const int NW = MTPB / 64;                 // 8 waves

    if (b == 0 && tid == 0) *ticket = 0u;     // consumed by K3 (two kernels later)

    extern __shared__ char smem[];
    float* ovl_s = (float*)smem;                                   // P floats
    unsigned char* obj_s = (unsigned char*)(smem + (size_t)P * 4); // P bytes
    char* base2 = smem + (size_t)P * 4 + (size_t)((P + 15) & ~15);
    float* sbox2 = (float*)base2;                       // [4][NOBJ] cx,cy,w,h
    int*   s_lab = (int*)(base2 + 4 * NOBJ * 4);        // [NOBJ]
    float* redv  = (float*)(base2 + 5 * NOBJ * 4);      // [NOBJ][NW]
    int*   redp  = (int*)(base2 + (5 + NW) * NOBJ * 4); // [NOBJ][NW]
    int*   pf    = (int*)(base2 + (5 + 2 * NW) * NOBJ * 4); // [NOBJ]
    int*   s_cnt = pf + NOBJ;
    float* s_lsum = (float*)(s_cnt + 1);

    // ---- hoist all pass-1 box data into registers (uniform loads) ---------
    float bx1[NOBJ], by1[NOBJ], bx2[NOBJ], by2[NOBJ], bar[NOBJ];
#pragma unroll
    for (int o = 0; o < NOBJ; o++) {
        const float4 bx = ((const float4*)boxes)[(size_t)b * NOBJ + o];
        bx1[o] = bx.x; by1[o] = bx.y;
        bx2[o] = bx.x + bx.z; by2[o] = bx.y + bx.w;
        bar[o] = (bx2[o] - bx1[o]) * (by2[o] - by1[o]);
    }
    // small LDS table for pass 2 (runtime-indexed by o)
    if (tid < NOBJ) {
        sbox2[0 * NOBJ + tid] = (bx1[tid] + bx2[tid]) * 0.5f;  // cx
        sbox2[1 * NOBJ + tid] = (by1[tid] + by2[tid]) * 0.5f;  // cy
        sbox2[2 * NOBJ + tid] = bx2[tid] - bx1[tid];           // w
        sbox2[3 * NOBJ + tid] = by2[tid] - by1[tid];           // h
        s_lab[tid] = labels[b * NOBJ + tid];
        if (tid == 0) { *s_cnt = 0; *s_lsum = 0.f; }
    }

    // --- pass 1: IoU, per-prior best object, per-object best prior ---------
    float bestv[NOBJ];
    int bestp[NOBJ];
#pragma unroll
    for (int o = 0; o < NOBJ; o++) { bestv[o] = -1.f; bestp[o] = 0x7fffffff; }

    for (int p = tid; p < P; p += MTPB) {
        float4 pr = ((const float4*)priors)[p];
        float hx = pr.z * 0.5f, hy = pr.w * 0.5f;
        float px1 = pr.x - hx, py1 = pr.y - hy;
        float px2 = pr.x + hx, py2 = pr.y + hy;
        float parea = (px2 - px1) * (py2 - py1);
        float bv = -1.f; int bo = 0;
#pragma unroll
        for (int o = 0; o < NOBJ; o++) {
            float ltx = fmaxf(bx1[o], px1);
            float lty = fmaxf(by1[o], py1);
            float rbx = fminf(bx2[o], px2);
            float rby = fminf(by2[o], py2);
            float w = rbx - ltx; w = w > 0.f ? w : 0.f;
            float h = rby - lty; h = h > 0.f ? h : 0.f;
            float inter = w * h;
            float iou = __fdividef(inter, bar[o] + parea - inter);
            if (iou > bv) { bv = iou; bo = o; }            // first-max (strict >)
            if (iou > bestv[o]) { bestv[o] = iou; bestp[o] = p; }
        }
        ovl_s[p] = bv;
        obj_s[p] = (unsigned char)bo;
    }

    // --- per-object argmax over priors ------------------------------------
#pragma unroll
    for (int o = 0; o < NOBJ; o++) {
        float v = bestv[o]; int pp = bestp[o];
#pragma unroll
        for (int d = 1; d < 64; d <<= 1) {
            float v2 = __shfl_xor(v, d);
            int   q2 = __shfl_xor(pp, d);
            if (v2 > v || (v2 == v && q2 < pp)) { v = v2; pp = q2; }
        }
        if ((tid & 63) == 0) {
            redv[o * NW + (tid >> 6)] = v;
            redp[o * NW + (tid >> 6)] = pp;
        }
    }
    __syncthreads();

    if (tid < NOBJ) {
        float v = -2.f; int pp = 0x7fffffff;
        for (int w = 0; w < NW; w++) {
            float v2 = redv[tid * NW + w];
            int   q2 = redp[tid * NW + w];
            if (v2 > v || (v2 == v && q2 < pp)) { v = v2; pp = q2; }
        }
        pf[tid] = pp;
    }
    __syncthreads();

    // forced assignment (sequential: duplicate best-priors -> last wins)
    if (tid == 0) {
        for (int i = 0; i < NOBJ; i++) {
            int pp = pf[i];
            obj_s[pp] = (unsigned char)i;
            ovl_s[pp] = 1.0f;
        }
    }
    __syncthreads();

    // --- pass 2: labels / flags / fused localization loss ------------------
    int cnt = 0;
    float lsum = 0.f;
    for (int p = tid; p < P; p += MTPB) {
        float ovl = ovl_s[p];
        int o = obj_s[p];
        int lab = s_lab[o];
        if (ovl < 0.5f) lab = 0;
        bool ign = (ovl > 0.4f) && (ovl < 0.5f);
        bool pos = (lab > 0) && !ign;
        meta[(size_t)b * P + p] = (unsigned)lab | (pos ? 256u : 0u) | (ign ? 512u : 0u);
        if (pos) {
            cnt++;
            float4 pr = ((const float4*)priors)[p];
            float cx = sbox2[0 * NOBJ + o], cy = sbox2[1 * NOBJ + o];
            float bw = sbox2[2 * NOBJ + o], bh = sbox2[3 * NOBJ + o];
            float g0 = (cx - pr.x) / (pr.z / 10.0f);
            float g1 = (cy - pr.y) / (pr.w / 10.0f);
            float g2 = __logf(fabsf(bw / pr.z)) * 5.0f;
            float g3 = __logf(fabsf(bh / pr.w)) * 5.0f;
            float4 pl = ((const float4*)plocs)[(size_t)b * P + p];
            lsum += sl1(pl.x - g0) + sl1(pl.y - g1) + sl1(pl.z - g2) + sl1(pl.w - g3);
        }
    }
#pragma unroll
    for (int d = 1; d < 64; d <<= 1) {
        lsum += __shfl_xor(lsum, d);
        cnt  += __shfl_xor(cnt, d);
    }
    if ((tid & 63) == 0) {
        atomicAdd(s_cnt, cnt);
        atomicAdd(s_lsum, lsum);
    }
    __syncthreads();
    if (tid == 0) {
        n_pos[b] = *s_cnt;
        loc_sum[b] = *s_lsum;
    }
}

// ---------------------------------------------------------------------------
// K2: cross-entropy, direct global->register (no LDS staging, no barrier).
// 16-lane group per row; grid-stride over 16-row tiles. The label score is
// picked from the group's own registers (cndmask chain + one shuffle).
// Requires C <= 96 (bench: C=91).
// ---------------------------------------------------------------------------
__global__ __launch_bounds__(TPB)
void k_ce(const float* __restrict__ scores, const unsigned* __restrict__ meta,
          int BP, int C, float* __restrict__ ce_neg, float* __restrict__ pos_blk)
{
    const int tid = threadIdx.x;
    const int g = tid >> 4;              // group within block (16 groups)
    const int wg = (tid >> 4) & 3;       // group within wave (4 groups)
    const int l = tid & 15;
    const int tiles = BP >> 4;           // BP divisible by 16 (B*P = 64*8732)

    float psum = 0.f;

    for (int t = blockIdx.x; t < tiles; t += gridDim.x) {
        const int row = (t << 4) + g;
        const unsigned mt = meta[row];   // issued early; broadcast in-group
        const float* s = scores + (size_t)row * C;

        float v[6];
        float m = -INFINITY;
#pragma unroll
        for (int j = 0; j < 6; j++) {
            int idx = l + (j << 4);
            v[j] = (idx < C) ? s[idx] : -INFINITY;
            m = fmaxf(m, v[j]);
        }
#pragma unroll
        for (int d = 1; d < 16; d <<= 1) m = fmaxf(m, __shfl_xor(m, d));

        float se = 0.f;
#pragma unroll
        for (int j = 0; j < 6; j++) se += __expf(v[j] - m);
#pragma unroll
        for (int d = 1; d < 16; d <<= 1) se += __shfl_xor(se, d);

        const int lab = (int)(mt & 255u);
        // static-index select of v[lab>>4] (rule #20: no dynamic reg indexing)
        float pick = v[0];
#pragma unroll
        for (int j = 1; j < 6; j++) pick = ((lab >> 4) == j) ? v[j] : pick;
        float sv = __shfl(pick, (wg << 4) | (lab & 15));   // wave-relative lane

        if (l == 0) {
            float ce = __logf(se) + m - sv;
            bool pos = (mt >> 8) & 1u;
            bool ign = (mt >> 9) & 1u;
            ce_neg[row] = (pos || ign) ? 0.f : ce;
            if (pos) psum += ce;
        }
    }

    // block-reduce psum (only lane0s hold nonzero; others are 0)
#pragma unroll
    for (int d = 1; d < 64; d <<= 1) psum += __shfl_xor(psum, d);
    __shared__ float sp[4];
    if ((tid & 63) == 0) sp[tid >> 6] = psum;
    __syncthreads();
    if (tid == 0) pos_blk[blockIdx.x] = sp[0] + sp[1] + sp[2] + sp[3];
}

// ---------------------------------------------------------------------------
// K3: per-row exact radix-select (4x8-bit, msb first) for sum of top-k of
// ce_neg (k = 3*n_pos), fused with the final combine in the last-arriving
// block (device-scope ticket; hard[] via atomicExch / atomic-read).
//  - row register-cached (static-unrolled vals[ITEMS], no dynamic indexing)
//  - pass 1 (exponent byte) uses ballot/leader wave-aggregation: ce values
//    cluster in 2-3 exponent bins, so plain LDS atomics would serialize
//    ~64-way; leader loop does one atomic per distinct bin per wave.
//  - passes 2-4: plain atomics on a single histogram copy (bins spread).
// ---------------------------------------------------------------------------
template<int ITEMS>
__global__ __launch_bounds__(MTPB)
void k_topk_final(const float* __restrict__ ce_neg, const int* __restrict__ n_pos,
                  const float* __restrict__ loc_sum, const float* __restrict__ pos_blk,
                  int nposblk, int P, int B,
                  float* __restrict__ hard, unsigned* __restrict__ ticket,
                  float* __restrict__ out)
{
    const int b = blockIdx.x;
    const int tid = threadIdx.x;
    const float* row = ce_neg + (size_t)b * P;
    __shared__ unsigned cnt[256];
    __shared__ float sm[256];
    __shared__ float s_sumhigh;
    __shared__ unsigned s_pref;
    __shared__ int s_krem;
    __shared__ bool s_last;

    int k = 3 * n_pos[b];
    if (k > P) k = P;

    // register-cache the row (static indexing only)
    float vals[ITEMS];
#pragma unroll
    for (int i = 0; i < ITEMS; i++) {
        int p = tid + i * MTPB;
        vals[i] = (p < P) ? row[p] : 0.f;
    }

    float hard_b = 0.f;
    if (k > 0) {
        if (tid == 0) { s_sumhigh = 0.f; s_pref = 0u; s_krem = k; }

        for (int shift = 24; shift >= 0; shift -= 8) {
            if (tid < 256) { cnt[tid] = 0u; sm[tid] = 0.f; }
            __syncthreads();

            if (shift == 24) {
                // ---- ballot/leader aggregation (few distinct bins) --------
#pragma unroll
                for (int i = 0; i < ITEMS; i++) {
                    int p = tid + i * MTPB;
                    float vv = vals[i];
                    unsigned bin = __float_as_uint(vv) >> 24;
                    bool done = (p >= P);
                    while (__any(!done)) {
                        unsigned long long act = __ballot(!done);
                        int leader = (int)__ffsll(act) - 1;
                        unsigned lb = (unsigned)__shfl((int)bin, leader);
                        bool mine = (!done) && (bin == lb);
                        float contrib = mine ? vv : 0.f;
#pragma unroll
                        for (int d = 1; d < 64; d <<= 1)
                            contrib += __shfl_xor(contrib, d);
                        unsigned long long grp = __ballot(mine);
                        if ((tid & 63) == leader) {
                            atomicAdd(&cnt[lb], (unsigned)__popcll(grp));
                            atomicAdd(&sm[lb], contrib);
                        }
                        done = done || mine;
                    }
                }
            } else {
                unsigned pref = s_pref;
                const int high = shift + 8;
#pragma unroll
                for (int i = 0; i < ITEMS; i++) {
                    int p = tid + i * MTPB;
                    float vv = vals[i];
                    unsigned u = __float_as_uint(vv);
                    if (p < P && ((u >> high) == (pref >> high))) {
                        unsigned bin = (u >> shift) & 255u;
                        atomicAdd(&cnt[bin], 1u);
                        atomicAdd(&sm[bin], vv);
                    }
                }
            }
            __syncthreads();
            if (tid == 0) {
                int krem = s_krem;
                float sh = s_sumhigh;
                unsigned p2 = s_pref;
                for (int bin = 255; bin >= 0; --bin) {
                    if ((int)cnt[bin] < krem) { krem -= (int)cnt[bin]; sh += sm[bin]; }
                    else { p2 |= ((unsigned)bin) << shift; break; }
                }
                s_krem = krem; s_sumhigh = sh; s_pref = p2;
            }
            __syncthreads();
        }
        if (tid == 0) {
            float t = __uint_as_float(s_pref);
            hard_b = s_sumhigh + (float)s_krem * t;
        }
    }

    // ---- publish + ticket (device-scope) ----------------------------------
    if (tid == 0) {
        atomicExch(&hard[b], hard_b);      // coherent publish
        __threadfence();                    // order publish before ticket
        unsigned old = atomicAdd(ticket, 1u);
        s_last = (old == (unsigned)(gridDim.x - 1));
    }
    __syncthreads();
    if (!s_last) return;

    // ---- fused final combine (last block only) -----------------------------
    __threadfence();
    float hd = (tid < B) ? atomicAdd(&hard[tid], 0.f) : 0.f;  // coherent read
    float lc = (tid < B) ? loc_sum[tid] : 0.f;                // prior-kernel data
    int   np = (tid < B) ? n_pos[tid] : 0;
    float ps = 0.f;
    for (int i = tid; i < nposblk; i += MTPB) ps += pos_blk[i];

#pragma unroll
    for (int d = 1; d < 64; d <<= 1) {
        hd += __shfl_xor(hd, d);
        lc += __shfl_xor(lc, d);
        ps += __shfl_xor(ps, d);
        np += __shfl_xor(np, d);
    }
    if ((tid & 63) == 0) {
        int wv = tid >> 6;
        sm[wv] = hd; sm[8 + wv] = lc; sm[16 + wv] = ps;
        cnt[wv] = (unsigned)np;
    }
    __syncthreads();
    if (tid == 0) {
        float thd = 0.f, tlc = 0.f, tps = 0.f; unsigned tnp = 0u;
        for (int wv = 0; wv < MTPB / 64; wv++) {
            thd += sm[wv]; tlc += sm[8 + wv]; tps += sm[16 + wv]; tnp += cnt[wv];
        }
        float n = (float)tnp;
        float conf = (thd + tps) / n;
        float loc = tlc / (n * 4.0f);
        out[0] = conf + loc;
        out[1] = conf;
        out[2] = loc;
    }
}

extern "C" void kernel_launch(void* const* d_in, const int* in_sizes, int n_in,
                              void* d_out, int out_size, void* d_ws, size_t ws_size,
                              hipStream_t stream)
{
    const float* plocs  = (const float*)d_in[0];   // [B,P,4]
    const float* scores = (const float*)d_in[1];   // [B,P,C]
    const float* boxes  = (const float*)d_in[2];   // [B,NOBJ,4] xywh
    const int*   labels = (const int*)d_in[3];     // [B,NOBJ]
    const float* priors = (const float*)d_in[4];   // [P,4] cxcy

    const int P = in_sizes[4] / 4;
    const int B = in_sizes[0] / (P * 4);
    const int C = in_sizes[1] / (B * P);
    const int BP = B * P;

    char* ws = (char*)d_ws;
    float*    loc_sum = (float*)ws;                          // [B]
    int*      n_pos   = (int*)(ws + 1024);                   // [B]
    float*    hard    = (float*)(ws + 2048);                 // [B]
    unsigned* ticket  = (unsigned*)(ws + 3072);              // 1
    unsigned* meta    = (unsigned*)(ws + 4096);              // [BP]
    float*    ce_neg  = (float*)(ws + 4096 + (size_t)BP * 4);// [BP]
    float*    pos_blk = (float*)(ws + 4096 + (size_t)BP * 8);// [CE_BLOCKS]

    size_t ldsA = (size_t)P * 4 + (size_t)((P + 15) & ~15) + 2048;
    k_match<16><<<B, MTPB, ldsA, stream>>>(boxes, labels, priors, plocs,
                                           P, meta, n_pos, loc_sum, ticket);

    k_ce<<<CE_BLOCKS, TPB, 0, stream>>>(scores, meta, BP, C, ce_neg, pos_blk);

    if (P <= MTPB * 18) {
        k_topk_final<18><<<B, MTPB, 0, stream>>>(ce_neg, n_pos, loc_sum, pos_blk,
                                                 CE_BLOCKS, P, B, hard, ticket,
                                                 (float*)d_out);
    } else {
        k_topk_final<36><<<B, MTPB, 0, stream>>>(ce_neg, n_pos, loc_sum, pos_blk,
                                                 CE_BLOCKS, P, B, hard, ticket,
                                                 (float*)d_out);
    }
}

// Round 6
// 133.171 us; speedup vs baseline: 1.8781x; 1.2215x over previous
//
#include <hip/hip_runtime.h>
#include <math.h>

#define TPB 256
#define MTPB 512       // match / topk block size
#define CE_BLOCKS 2048 // k_ce grid (8 blocks/CU on 256 CUs)
#define SEGS 4         // priors-segments per batch row for match kernels

__device__ __forceinline__ float sl1(float x) {
    float a = fabsf(x);
    return a < 1.f ? 0.5f * a * a : a - 0.5f;
}

// ---------------------------------------------------------------------------
// K1a: segment IoU pass. Grid = B*SEGS blocks (fills all 256 CUs).
// Block (b,s) computes, for priors in its segment: per-prior best object ->
// ovl_g/obj_g (global), and per-object best prior within the segment ->
// segv/segp. Also zeroes the ticket consumed by K3.
// ---------------------------------------------------------------------------
template<int NOBJ>
__global__ __launch_bounds__(MTPB)
void k_match_iou(const float* __restrict__ boxes, const float* __restrict__ priors,
                 int P, float* __restrict__ ovl_g, unsigned char* __restrict__ obj_g,
                 float* __restrict__ segv, int* __restrict__ segp,
                 unsigned* __restrict__ ticket)
{
    const int bs = blockIdx.x;
    const int b = bs >> 2;               // SEGS == 4
    const int s = bs & 3;
    const int tid = threadIdx.x;
    const int NW = MTPB / 64;            // 8 waves

    if (bs == 0 && tid == 0) *ticket = 0u;

    __shared__ float redv[NOBJ * (MTPB / 64)];
    __shared__ int   redp[NOBJ * (MTPB / 64)];

    const int seglen = (P + SEGS - 1) / SEGS;
    const int p0 = s * seglen;
    const int p1 = min(p0 + seglen, P);

    // box data in registers (unrolled o -> static indexing, uniform loads)
    float bx1[NOBJ], by1[NOBJ], bx2[NOBJ], by2[NOBJ], bar[NOBJ];
#pragma unroll
    for (int o = 0; o < NOBJ; o++) {
        const float4 bx = ((const float4*)boxes)[(size_t)b * NOBJ + o];
        bx1[o] = bx.x; by1[o] = bx.y;
        bx2[o] = bx.x + bx.z; by2[o] = bx.y + bx.w;
        bar[o] = (bx2[o] - bx1[o]) * (by2[o] - by1[o]);
    }

    float bestv[NOBJ];
    int bestp[NOBJ];
#pragma unroll
    for (int o = 0; o < NOBJ; o++) { bestv[o] = -1.f; bestp[o] = 0x7fffffff; }

    for (int p = p0 + tid; p < p1; p += MTPB) {
        float4 pr = ((const float4*)priors)[p];
        float hx = pr.z * 0.5f, hy = pr.w * 0.5f;
        float px1 = pr.x - hx, py1 = pr.y - hy;
        float px2 = pr.x + hx, py2 = pr.y + hy;
        float parea = (px2 - px1) * (py2 - py1);
        float bv = -1.f; int bo = 0;
#pragma unroll
        for (int o = 0; o < NOBJ; o++) {
            float ltx = fmaxf(bx1[o], px1);
            float lty = fmaxf(by1[o], py1);
            float rbx = fminf(bx2[o], px2);
            float rby = fminf(by2[o], py2);
            float w = rbx - ltx; w = w > 0.f ? w : 0.f;
            float h = rby - lty; h = h > 0.f ? h : 0.f;
            float inter = w * h;
            float iou = __fdividef(inter, bar[o] + parea - inter);
            if (iou > bv) { bv = iou; bo = o; }            // first-max (strict >)
            if (iou > bestv[o]) { bestv[o] = iou; bestp[o] = p; }
        }
        ovl_g[(size_t)b * P + p] = bv;
        obj_g[(size_t)b * P + p] = (unsigned char)bo;
    }

    // per-object argmax within segment: wave reduce, then cross-wave
#pragma unroll
    for (int o = 0; o < NOBJ; o++) {
        float v = bestv[o]; int pp = bestp[o];
#pragma unroll
        for (int d = 1; d < 64; d <<= 1) {
            float v2 = __shfl_xor(v, d);
            int   q2 = __shfl_xor(pp, d);
            if (v2 > v || (v2 == v && q2 < pp)) { v = v2; pp = q2; }
        }
        if ((tid & 63) == 0) {
            redv[o * NW + (tid >> 6)] = v;
            redp[o * NW + (tid >> 6)] = pp;
        }
    }
    __syncthreads();

    if (tid < NOBJ) {
        float v = -2.f; int pp = 0x7fffffff;
        for (int w = 0; w < NW; w++) {
            float v2 = redv[tid * NW + w];
            int   q2 = redp[tid * NW + w];
            if (v2 > v || (v2 == v && q2 < pp)) { v = v2; pp = q2; }
        }
        segv[((size_t)b * NOBJ + tid) * SEGS + s] = v;
        segp[((size_t)b * NOBJ + tid) * SEGS + s] = pp;
    }
}

// ---------------------------------------------------------------------------
// K1b: finalize match. Grid = B*SEGS blocks. Every block replicates the tiny
// per-object merge over segments (16 objs x 4 segs), then does pass-2 on its
// segment with the forced assignment applied INLINE (p compared against the
// 16 forced priors, ascending i -> last-wins, matching scatter semantics).
// Outputs: meta, n_pos_seg[b*SEGS+s], loc_seg[b*SEGS+s].
// ---------------------------------------------------------------------------
template<int NOBJ>
__global__ __launch_bounds__(MTPB)
void k_match_fin(const float* __restrict__ boxes, const int* __restrict__ labels,
                 const float* __restrict__ priors, const float* __restrict__ plocs,
                 const float* __restrict__ ovl_g, const unsigned char* __restrict__ obj_g,
                 const float* __restrict__ segv, const int* __restrict__ segp,
                 int P, unsigned* __restrict__ meta,
                 int* __restrict__ n_pos_seg, float* __restrict__ loc_seg)
{
    const int bs = blockIdx.x;
    const int b = bs >> 2;
    const int s = bs & 3;
    const int tid = threadIdx.x;

    __shared__ float sbox2[4 * NOBJ];
    __shared__ int s_lab[NOBJ];
    __shared__ int pf[NOBJ];
    __shared__ int s_cnt;
    __shared__ float s_lsum;

    if (tid < NOBJ) {
        const float4 bx = ((const float4*)boxes)[(size_t)b * NOBJ + tid];
        float x1 = bx.x, y1 = bx.y, x2 = bx.x + bx.z, y2 = bx.y + bx.w;
        sbox2[0 * NOBJ + tid] = (x1 + x2) * 0.5f;   // cx
        sbox2[1 * NOBJ + tid] = (y1 + y2) * 0.5f;   // cy
        sbox2[2 * NOBJ + tid] = x2 - x1;            // w
        sbox2[3 * NOBJ + tid] = y2 - y1;            // h
        s_lab[tid] = labels[b * NOBJ + tid];
        // merge per-object best over segments (strict >, tie -> smaller idx)
        float v = -2.f; int pp = 0x7fffffff;
#pragma unroll
        for (int ss = 0; ss < SEGS; ss++) {
            float v2 = segv[((size_t)b * NOBJ + tid) * SEGS + ss];
            int   q2 = segp[((size_t)b * NOBJ + tid) * SEGS + ss];
            if (v2 > v || (v2 == v && q2 < pp)) { v = v2; pp = q2; }
        }
        pf[tid] = pp;
        if (tid == 0) { s_cnt = 0; s_lsum = 0.f; }
    }
    __syncthreads();

    const int seglen = (P + SEGS - 1) / SEGS;
    const int p0 = s * seglen;
    const int p1 = min(p0 + seglen, P);

    int cnt = 0;
    float lsum = 0.f;
    for (int p = p0 + tid; p < p1; p += MTPB) {
        float ovl = ovl_g[(size_t)b * P + p];
        int o = obj_g[(size_t)b * P + p];
        // inline forced assignment (last-wins over i)
        int fo = -1;
#pragma unroll
        for (int i = 0; i < NOBJ; i++) if (pf[i] == p) fo = i;
        if (fo >= 0) { ovl = 1.0f; o = fo; }

        int lab = s_lab[o];
        if (ovl < 0.5f) lab = 0;
        bool ign = (ovl > 0.4f) && (ovl < 0.5f);
        bool pos = (lab > 0) && !ign;
        meta[(size_t)b * P + p] = (unsigned)lab | (pos ? 256u : 0u) | (ign ? 512u : 0u);
        if (pos) {
            cnt++;
            float4 pr = ((const float4*)priors)[p];
            float cx = sbox2[0 * NOBJ + o], cy = sbox2[1 * NOBJ + o];
            float bw = sbox2[2 * NOBJ + o], bh = sbox2[3 * NOBJ + o];
            float g0 = (cx - pr.x) / (pr.z / 10.0f);
            float g1 = (cy - pr.y) / (pr.w / 10.0f);
            float g2 = __logf(fabsf(bw / pr.z)) * 5.0f;
            float g3 = __logf(fabsf(bh / pr.w)) * 5.0f;
            float4 pl = ((const float4*)plocs)[(size_t)b * P + p];
            lsum += sl1(pl.x - g0) + sl1(pl.y - g1) + sl1(pl.z - g2) + sl1(pl.w - g3);
        }
    }
#pragma unroll
    for (int d = 1; d < 64; d <<= 1) {
        lsum += __shfl_xor(lsum, d);
        cnt  += __shfl_xor(cnt, d);
    }
    if ((tid & 63) == 0) {
        atomicAdd(&s_cnt, cnt);
        atomicAdd(&s_lsum, lsum);
    }
    __syncthreads();
    if (tid == 0) {
        n_pos_seg[bs] = s_cnt;
        loc_seg[bs] = s_lsum;
    }
}

// ---------------------------------------------------------------------------
// K2 fast path (C == 91): 4 rows = exactly 91 float4 and every 4-row quad is
// 16B-aligned. Each wave stages its row-quad with dwordx4 loads into a
// private 1456B LDS slot (wave-coherent: no __syncthreads), then its 4
// 16-lane groups compute logsumexp from LDS; s[lab] is a single ds_read.
// ---------------------------------------------------------------------------
__global__ __launch_bounds__(TPB)
void k_ce91(const float* __restrict__ scores, const unsigned* __restrict__ meta,
            int BP, float* __restrict__ ce_neg, float* __restrict__ pos_blk)
{
    __shared__ __align__(16) float sf[4 * 364];   // 4 waves x 91 float4
    __shared__ float sp[4];

    const int tid = threadIdx.x;
    const int wid = tid >> 6;
    const int lane = tid & 63;
    const int g = (tid >> 4) & 3;        // group within wave
    const int l = tid & 15;
    float* wlds = sf + wid * 364;

    const int nquads = BP >> 2;          // BP divisible by 4
    const int gwaves = gridDim.x * (TPB / 64);
    const float4* src = (const float4*)scores;

    float psum = 0.f;

    for (int q = blockIdx.x * (TPB / 64) + wid; q < nquads; q += gwaves) {
        // --- stage quad: 91 float4, 16B-aligned ---
        float4 ra = src[(size_t)q * 91 + lane];
        float4 rb = make_float4(0.f, 0.f, 0.f, 0.f);
        if (lane < 27) rb = src[(size_t)q * 91 + 64 + lane];
        unsigned mt = 0u;
        if (l == 0) mt = meta[(q << 2) + g];

        ((float4*)wlds)[lane] = ra;
        if (lane < 27) ((float4*)wlds)[64 + lane] = rb;
        // wave-coherent LDS: compiler inserts lgkmcnt before the reads below

        // --- per-row logsumexp from LDS ---
        const float* rowp = wlds + g * 91;
        float v[6];
        float m = -INFINITY;
#pragma unroll
        for (int j = 0; j < 6; j++) {
            int idx = l + (j << 4);
            v[j] = (idx < 91) ? rowp[idx] : -INFINITY;
            m = fmaxf(m, v[j]);
        }
#pragma unroll
        for (int d = 1; d < 16; d <<= 1) m = fmaxf(m, __shfl_xor(m, d));

        float se = 0.f;
#pragma unroll
        for (int j = 0; j < 6; j++) se += __expf(v[j] - m);
#pragma unroll
        for (int d = 1; d < 16; d <<= 1) se += __shfl_xor(se, d);

        if (l == 0) {
            int lab = (int)(mt & 255u);
            float sv = rowp[lab];
            float ce = __logf(se) + m - sv;
            bool pos = (mt >> 8) & 1u;
            bool ign = (mt >> 9) & 1u;
            ce_neg[(q << 2) + g] = (pos || ign) ? 0.f : ce;
            if (pos) psum += ce;
        }
    }

#pragma unroll
    for (int d = 1; d < 64; d <<= 1) psum += __shfl_xor(psum, d);
    if ((tid & 63) == 0) sp[tid >> 6] = psum;
    __syncthreads();
    if (tid == 0) pos_blk[blockIdx.x] = sp[0] + sp[1] + sp[2] + sp[3];
}

// ---------------------------------------------------------------------------
// K2 generic fallback (C != 91): direct global->register, as R4/R5.
// ---------------------------------------------------------------------------
__global__ __launch_bounds__(TPB)
void k_ce(const float* __restrict__ scores, const unsigned* __restrict__ meta,
          int BP, int C, float* __restrict__ ce_neg, float* __restrict__ pos_blk)
{
    const int tid = threadIdx.x;
    const int g = tid >> 4;
    const int wg = (tid >> 4) & 3;
    const int l = tid & 15;
    const int tiles = BP >> 4;

    float psum = 0.f;

    for (int t = blockIdx.x; t < tiles; t += gridDim.x) {
        const int row = (t << 4) + g;
        const unsigned mt = meta[row];
        const float* s = scores + (size_t)row * C;

        float v[6];
        float m = -INFINITY;
#pragma unroll
        for (int j = 0; j < 6; j++) {
            int idx = l + (j << 4);
            v[j] = (idx < C) ? s[idx] : -INFINITY;
            m = fmaxf(m, v[j]);
        }
#pragma unroll
        for (int d = 1; d < 16; d <<= 1) m = fmaxf(m, __shfl_xor(m, d));

        float se = 0.f;
#pragma unroll
        for (int j = 0; j < 6; j++) se += __expf(v[j] - m);
#pragma unroll
        for (int d = 1; d < 16; d <<= 1) se += __shfl_xor(se, d);

        const int lab = (int)(mt & 255u);
        float pick = v[0];
#pragma unroll
        for (int j = 1; j < 6; j++) pick = ((lab >> 4) == j) ? v[j] : pick;
        float sv = __shfl(pick, (wg << 4) | (lab & 15));

        if (l == 0) {
            float ce = __logf(se) + m - sv;
            bool pos = (mt >> 8) & 1u;
            bool ign = (mt >> 9) & 1u;
            ce_neg[row] = (pos || ign) ? 0.f : ce;
            if (pos) psum += ce;
        }
    }

#pragma unroll
    for (int d = 1; d < 64; d <<= 1) psum += __shfl_xor(psum, d);
    __shared__ float sp[4];
    if ((tid & 63) == 0) sp[tid >> 6] = psum;
    __syncthreads();
    if (tid == 0) pos_blk[blockIdx.x] = sp[0] + sp[1] + sp[2] + sp[3];
}

// ---------------------------------------------------------------------------
// K3: per-row exact radix-select (4x8-bit, msb first) for sum of top-k of
// ce_neg (k = 3*n_pos), fused with the final combine in the last-arriving
// block. Row register-cached; pass 1 uses ballot/leader wave-aggregation.
// ---------------------------------------------------------------------------
template<int ITEMS>
__global__ __launch_bounds__(MTPB)
void k_topk_final(const float* __restrict__ ce_neg, const int* __restrict__ n_pos_seg,
                  const float* __restrict__ loc_seg, const float* __restrict__ pos_blk,
                  int nposblk, int P, int B,
                  float* __restrict__ hard, unsigned* __restrict__ ticket,
                  float* __restrict__ out)
{
    const int b = blockIdx.x;
    const int tid = threadIdx.x;
    const float* row = ce_neg + (size_t)b * P;
    __shared__ unsigned cnt[256];
    __shared__ float sm[256];
    __shared__ float s_sumhigh;
    __shared__ unsigned s_pref;
    __shared__ int s_krem;
    __shared__ bool s_last;

    int k = 0;
#pragma unroll
    for (int s = 0; s < SEGS; s++) k += n_pos_seg[b * SEGS + s];
    k *= 3;
    if (k > P) k = P;

    // register-cache the row (static indexing only)
    float vals[ITEMS];
#pragma unroll
    for (int i = 0; i < ITEMS; i++) {
        int p = tid + i * MTPB;
        vals[i] = (p < P) ? row[p] : 0.f;
    }

    float hard_b = 0.f;
    if (k > 0) {
        if (tid == 0) { s_sumhigh = 0.f; s_pref = 0u; s_krem = k; }

        for (int shift = 24; shift >= 0; shift -= 8) {
            if (tid < 256) { cnt[tid] = 0u; sm[tid] = 0.f; }
            __syncthreads();

            if (shift == 24) {
                // ballot/leader aggregation (few distinct exponent bins)
#pragma unroll
                for (int i = 0; i < ITEMS; i++) {
                    int p = tid + i * MTPB;
                    float vv = vals[i];
                    unsigned bin = __float_as_uint(vv) >> 24;
                    bool done = (p >= P);
                    while (__any(!done)) {
                        unsigned long long act = __ballot(!done);
                        int leader = (int)__ffsll(act) - 1;
                        unsigned lb = (unsigned)__shfl((int)bin, leader);
                        bool mine = (!done) && (bin == lb);
                        float contrib = mine ? vv : 0.f;
#pragma unroll
                        for (int d = 1; d < 64; d <<= 1)
                            contrib += __shfl_xor(contrib, d);
                        unsigned long long grp = __ballot(mine);
                        if ((tid & 63) == leader) {
                            atomicAdd(&cnt[lb], (unsigned)__popcll(grp));
                            atomicAdd(&sm[lb], contrib);
                        }
                        done = done || mine;
                    }
                }
            } else {
                unsigned pref = s_pref;
                const int high = shift + 8;
#pragma unroll
                for (int i = 0; i < ITEMS; i++) {
                    int p = tid + i * MTPB;
                    float vv = vals[i];
                    unsigned u = __float_as_uint(vv);
                    if (p < P && ((u >> high) == (pref >> high))) {
                        unsigned bin = (u >> shift) & 255u;
                        atomicAdd(&cnt[bin], 1u);
                        atomicAdd(&sm[bin], vv);
                    }
                }
            }
            __syncthreads();
            if (tid == 0) {
                int krem = s_krem;
                float sh = s_sumhigh;
                unsigned p2 = s_pref;
                for (int bin = 255; bin >= 0; --bin) {
                    if ((int)cnt[bin] < krem) { krem -= (int)cnt[bin]; sh += sm[bin]; }
                    else { p2 |= ((unsigned)bin) << shift; break; }
                }
                s_krem = krem; s_sumhigh = sh; s_pref = p2;
            }
            __syncthreads();
        }
        if (tid == 0) {
            float t = __uint_as_float(s_pref);
            hard_b = s_sumhigh + (float)s_krem * t;
        }
    }

    // ---- publish + ticket (device-scope) ----------------------------------
    if (tid == 0) {
        atomicExch(&hard[b], hard_b);      // coherent publish
        __threadfence();                    // order publish before ticket
        unsigned old = atomicAdd(ticket, 1u);
        s_last = (old == (unsigned)(gridDim.x - 1));
    }
    __syncthreads();
    if (!s_last) return;

    // ---- fused final combine (last block only) -----------------------------
    __threadfence();
    float hd = (tid < B) ? atomicAdd(&hard[tid], 0.f) : 0.f;  // coherent read
    float lc = 0.f; int np = 0;
    for (int i = tid; i < B * SEGS; i += MTPB) {
        lc += loc_seg[i];
        np += n_pos_seg[i];
    }
    float ps = 0.f;
    for (int i = tid; i < nposblk; i += MTPB) ps += pos_blk[i];

#pragma unroll
    for (int d = 1; d < 64; d <<= 1) {
        hd += __shfl_xor(hd, d);
        lc += __shfl_xor(lc, d);
        ps += __shfl_xor(ps, d);
        np += __shfl_xor(np, d);
    }
    if ((tid & 63) == 0) {
        int wv = tid >> 6;
        sm[wv] = hd; sm[8 + wv] = lc; sm[16 + wv] = ps;
        cnt[wv] = (unsigned)np;
    }
    __syncthreads();
    if (tid == 0) {
        float thd = 0.f, tlc = 0.f, tps = 0.f; unsigned tnp = 0u;
        for (int wv = 0; wv < MTPB / 64; wv++) {
            thd += sm[wv]; tlc += sm[8 + wv]; tps += sm[16 + wv]; tnp += cnt[wv];
        }
        float n = (float)tnp;
        float conf = (thd + tps) / n;
        float loc = tlc / (n * 4.0f);
        out[0] = conf + loc;
        out[1] = conf;
        out[2] = loc;
    }
}

extern "C" void kernel_launch(void* const* d_in, const int* in_sizes, int n_in,
                              void* d_out, int out_size, void* d_ws, size_t ws_size,
                              hipStream_t stream)
{
    const float* plocs  = (const float*)d_in[0];   // [B,P,4]
    const float* scores = (const float*)d_in[1];   // [B,P,C]
    const float* boxes  = (const float*)d_in[2];   // [B,NOBJ,4] xywh
    const int*   labels = (const int*)d_in[3];     // [B,NOBJ]
    const float* priors = (const float*)d_in[4];   // [P,4] cxcy

    const int P = in_sizes[4] / 4;
    const int B = in_sizes[0] / (P * 4);
    const int C = in_sizes[1] / (B * P);
    const int BP = B * P;
    const int NOBJ = 16;

    char* ws = (char*)d_ws;
    float*    loc_seg   = (float*)ws;                         // [B*SEGS]
    int*      n_pos_seg = (int*)(ws + 1024);                  // [B*SEGS]
    float*    hard      = (float*)(ws + 2048);                // [B]
    unsigned* ticket    = (unsigned*)(ws + 3072);             // 1
    unsigned* meta      = (unsigned*)(ws + 4096);             // [BP]
    float*    ce_neg    = (float*)(ws + 4096 + (size_t)BP * 4);        // [BP]
    float*    pos_blk   = (float*)(ws + 4096 + (size_t)BP * 8);        // [CE_BLOCKS]
    char*     ws2       = ws + 4096 + (size_t)BP * 8 + 8192;
    float*    segv      = (float*)ws2;                        // [B*NOBJ*SEGS]
    int*      segp      = (int*)(ws2 + 16384);                // [B*NOBJ*SEGS]
    float*    ovl_g     = (float*)(ws2 + 32768);              // [BP]
    unsigned char* obj_g = (unsigned char*)(ws2 + 32768 + (size_t)BP * 4); // [BP]

    k_match_iou<16><<<B * SEGS, MTPB, 0, stream>>>(boxes, priors, P,
                                                   ovl_g, obj_g, segv, segp, ticket);

    k_match_fin<16><<<B * SEGS, MTPB, 0, stream>>>(boxes, labels, priors, plocs,
                                                   ovl_g, obj_g, segv, segp,
                                                   P, meta, n_pos_seg, loc_seg);

    if (C == 91 && (BP & 3) == 0) {
        k_ce91<<<CE_BLOCKS, TPB, 0, stream>>>(scores, meta, BP, ce_neg, pos_blk);
    } else {
        k_ce<<<CE_BLOCKS, TPB, 0, stream>>>(scores, meta, BP, C, ce_neg, pos_blk);
    }

    if (P <= MTPB * 18) {
        k_topk_final<18><<<B, MTPB, 0, stream>>>(ce_neg, n_pos_seg, loc_seg, pos_blk,
                                                 CE_BLOCKS, P, B, hard, ticket,
                                                 (float*)d_out);
    } else {
        k_topk_final<36><<<B, MTPB, 0, stream>>>(ce_neg, n_pos_seg, loc_seg, pos_blk,
                                                 CE_BLOCKS, P, B, hard, ticket,
                                                 (float*)d_out);
    }
}